// Round 4
// baseline (853.818 us; speedup 1.0000x reference)
//
#include <hip/hip_runtime.h>

constexpr int IN_DIM = 128;
constexpr int SCHUNK = 2048;  // elements per scan block (256 thr * 8)
constexpr int BSHIFT = 7;     // 128 nodes per bucket

// ---------- degree histogram (edges only; self-loop added analytically) ----------
__global__ void count_deg_k(const int* __restrict__ ei, int E, int* __restrict__ cnt) {
  int i = blockIdx.x * blockDim.x + threadIdx.x;
  int stride = gridDim.x * blockDim.x;
  for (; i < E; i += stride) {
    atomicAdd(&cnt[ei[E + i]], 1);
  }
}

__global__ void dinv_k(const int* __restrict__ cnt, float* __restrict__ dinv, int n) {
  int i = blockIdx.x * blockDim.x + threadIdx.x;
  if (i < n) dinv[i] = rsqrtf((float)cnt[i] + 1.0f);  // +1 self-loop
}

// ---------- hierarchical exclusive scan of cnt[0..n) ----------
__global__ __launch_bounds__(256)
void scan1_k(const int* __restrict__ cnt, int n, int* __restrict__ bsum) {
  __shared__ int sd[256];
  int base = blockIdx.x * SCHUNK + threadIdx.x * 8;
  int s = 0;
#pragma unroll
  for (int j = 0; j < 8; ++j) {
    int i = base + j;
    if (i < n) s += cnt[i];
  }
  sd[threadIdx.x] = s;
  __syncthreads();
  for (int ofs = 128; ofs > 0; ofs >>= 1) {
    if (threadIdx.x < ofs) sd[threadIdx.x] += sd[threadIdx.x + ofs];
    __syncthreads();
  }
  if (threadIdx.x == 0) bsum[blockIdx.x] = sd[0];
}

__global__ __launch_bounds__(256)
void scan2_k(int* __restrict__ bsum, int B, int* __restrict__ off, int n) {
  __shared__ int sd[256];
  int v = (threadIdx.x < B) ? bsum[threadIdx.x] : 0;
  sd[threadIdx.x] = v;
  __syncthreads();
#pragma unroll
  for (int ofs = 1; ofs < 256; ofs <<= 1) {
    int t = (threadIdx.x >= ofs) ? sd[threadIdx.x - ofs] : 0;
    __syncthreads();
    sd[threadIdx.x] += t;
    __syncthreads();
  }
  if (threadIdx.x < B) bsum[threadIdx.x] = sd[threadIdx.x] - v;  // exclusive
  if (threadIdx.x == 255) off[n] = sd[255];                      // total == E
}

__global__ __launch_bounds__(256)
void scan3_k(const int* __restrict__ cnt, int n, const int* __restrict__ bsum,
             int* __restrict__ off, int* __restrict__ cursor) {
  __shared__ int sd[256];
  int base = blockIdx.x * SCHUNK + threadIdx.x * 8;
  int v[8];
  int s = 0;
#pragma unroll
  for (int j = 0; j < 8; ++j) {
    int i = base + j;
    v[j] = (i < n) ? cnt[i] : 0;
    s += v[j];
  }
  sd[threadIdx.x] = s;
  __syncthreads();
#pragma unroll
  for (int ofs = 1; ofs < 256; ofs <<= 1) {
    int t = (threadIdx.x >= ofs) ? sd[threadIdx.x - ofs] : 0;
    __syncthreads();
    sd[threadIdx.x] += t;
    __syncthreads();
  }
  int running = bsum[blockIdx.x] + sd[threadIdx.x] - s;  // exclusive prefix
#pragma unroll
  for (int j = 0; j < 8; ++j) {
    int i = base + j;
    if (i < n) { off[i] = running; cursor[i] = running; }
    running += v[j];
  }
}

// ---------- bucketed CSR fill ----------
// bucket b = nodes [b<<BSHIFT, (b+1)<<BSHIFT); its CSR range is
// [off[b<<BSHIFT], off[min((b+1)<<BSHIFT, n)]) -- contiguous. bcur[b] starts there.
__global__ void binit_k(const int* __restrict__ off, int* __restrict__ bcur,
                        int NB, int n) {
  int b = blockIdx.x * blockDim.x + threadIdx.x;
  if (b <= NB) {
    int node = b << BSHIFT;
    if (node > n) node = n;
    bcur[b] = off[node];
  }
}

// pass 1: append packed (dst,src) into the dst's bucket range (locality-friendly writes)
__global__ void fill1_k(const int* __restrict__ ei, int E, int* __restrict__ bcur,
                        unsigned long long* __restrict__ pairs) {
  int i = blockIdx.x * blockDim.x + threadIdx.x;
  int stride = gridDim.x * blockDim.x;
  for (; i < E; i += stride) {
    int s = ei[i];
    int d = ei[E + i];
    int pos = atomicAdd(&bcur[d >> BSHIFT], 1);
    pairs[pos] = ((unsigned long long)(unsigned)d << 32) | (unsigned)s;
  }
}

// pass 2: one block per bucket; scatter src to exact per-node slots (8KB window per block)
__global__ __launch_bounds__(256)
void fill2_k(const int* __restrict__ off, const unsigned long long* __restrict__ pairs,
             int* __restrict__ cursor, int* __restrict__ ssrc, int n) {
  int node0 = blockIdx.x << BSHIFT;
  int node1 = node0 + (1 << BSHIFT);
  if (node1 > n) node1 = n;
  int beg = off[node0], end = off[node1];
  for (int i = beg + threadIdx.x; i < end; i += 256) {
    unsigned long long p = pairs[i];
    int s = (int)(unsigned)p;
    int d = (int)(p >> 32);
    int pos = atomicAdd(&cursor[d], 1);
    ssrc[pos] = s;
  }
}

// ---------- matmul with dinv row-scale epilogue ----------
template<int OUT>
__global__ __launch_bounds__(256)
void matmul_scale_k(const float* __restrict__ X, const float* __restrict__ W,
                    const float* __restrict__ dinv, float* __restrict__ HS, int n) {
  constexpr int COLS = 64;
  constexpr int OG = COLS / 4;     // 16 threads per row
  constexpr int RPP = 256 / OG;    // 16 rows per pass
  __shared__ float Ws[IN_DIM * COLS];  // 32 KB
  __shared__ float XS[RPP * IN_DIM];   // 8 KB
  const int col0 = blockIdx.y * COLS;

  for (int i = threadIdx.x; i < IN_DIM * COLS; i += 256) {
    int k = i / COLS, c = i % COLS;
    Ws[i] = W[k * OUT + col0 + c];
  }

  const int og = threadIdx.x % OG;
  const int r  = threadIdx.x / OG;
  const int o4 = og * 4;

  for (int row0 = blockIdx.x * RPP; row0 < n; row0 += gridDim.x * RPP) {
    __syncthreads();
    for (int i = threadIdx.x; i < RPP * IN_DIM; i += 256) {
      int row = row0 + (i / IN_DIM);
      XS[i] = (row < n) ? X[(long long)row * IN_DIM + (i % IN_DIM)] : 0.0f;
    }
    __syncthreads();

    float4 acc = make_float4(0.f, 0.f, 0.f, 0.f);
#pragma unroll
    for (int k = 0; k < IN_DIM; k += 4) {
      float4 xv = *(const float4*)&XS[r * IN_DIM + k];
      const float* wp = &Ws[k * COLS + o4];
      float4 w0 = *(const float4*)(wp);
      float4 w1 = *(const float4*)(wp + COLS);
      float4 w2 = *(const float4*)(wp + 2 * COLS);
      float4 w3 = *(const float4*)(wp + 3 * COLS);
      acc.x = fmaf(xv.x, w0.x, fmaf(xv.y, w1.x, fmaf(xv.z, w2.x, fmaf(xv.w, w3.x, acc.x))));
      acc.y = fmaf(xv.x, w0.y, fmaf(xv.y, w1.y, fmaf(xv.z, w2.y, fmaf(xv.w, w3.y, acc.y))));
      acc.z = fmaf(xv.x, w0.z, fmaf(xv.y, w1.z, fmaf(xv.z, w2.z, fmaf(xv.w, w3.z, acc.z))));
      acc.w = fmaf(xv.x, w0.w, fmaf(xv.y, w1.w, fmaf(xv.z, w2.w, fmaf(xv.w, w3.w, acc.w))));
    }
    int row = row0 + r;
    if (row < n) {
      float s = dinv[row];
      *(float4*)&HS[(long long)row * OUT + col0 + o4] =
          make_float4(acc.x * s, acc.y * s, acc.z * s, acc.w * s);
    }
  }
}

// ---------- CSR aggregate + fused finalize ----------
template<int OUT>
__global__ __launch_bounds__(256)
void aggregate_k(const int* __restrict__ off, const int* __restrict__ ssrc,
                 const float* __restrict__ HS, const float* __restrict__ dinv,
                 const float* __restrict__ bias, float* __restrict__ Y, int n) {
  constexpr int TPR = OUT / 4;       // lanes per row (32 or 16)
  constexpr int RPB = 256 / TPR;     // rows per block (8 or 16)
  const int lane = threadIdx.x % TPR;
  const int r    = threadIdx.x / TPR;
  const int o4   = lane * 4;
  const float4 bb = *(const float4*)&bias[o4];

  for (int d = blockIdx.x * RPB + r; d < n; d += gridDim.x * RPB) {
    int beg = off[d], end = off[d + 1];
    float4 acc = *(const float4*)&HS[(long long)d * OUT + o4];  // self-loop term
    for (int e = beg; e < end; ++e) {
      int s = ssrc[e];
      float4 v = *(const float4*)&HS[(long long)s * OUT + o4];
      acc.x += v.x; acc.y += v.y; acc.z += v.z; acc.w += v.w;
    }
    float di = dinv[d];
    float4 y;
    y.x = fmaxf(fmaf(di, acc.x, bb.x), 0.f);
    y.y = fmaxf(fmaf(di, acc.y, bb.y), 0.f);
    y.z = fmaxf(fmaf(di, acc.z, bb.z), 0.f);
    y.w = fmaxf(fmaf(di, acc.w, bb.w), 0.f);
    *(float4*)&Y[(long long)d * OUT + o4] = y;
  }
}

extern "C" void kernel_launch(void* const* d_in, const int* in_sizes, int n_in,
                              void* d_out, int out_size, void* d_ws, size_t ws_size,
                              hipStream_t stream) {
  const float* x  = (const float*)d_in[0];
  const int*   ei = (const int*)d_in[1];
  const float* W1 = (const float*)d_in[2];
  const float* b1 = (const float*)d_in[3];
  const float* W2 = (const float*)d_in[4];
  const float* b2 = (const float*)d_in[5];
  float* out = (float*)d_out;

  const int n = in_sizes[0] / IN_DIM;   // 100000
  const int E = in_sizes[1] / 2;        // 1600000

  // workspace layout (bytes)
  char* ws = (char*)d_ws;
  size_t o = 0;
  auto alloc = [&](size_t bytes) { char* p = ws + o; o = (o + bytes + 255) & ~(size_t)255; return p; };
  float* dinv   = (float*)alloc((size_t)n * 4);
  int*   off    = (int*)  alloc((size_t)(n + 1) * 4);
  int*   cursor = (int*)  alloc((size_t)n * 4);
  int*   cnt    = (int*)  alloc((size_t)n * 4);
  int*   bsum   = (int*)  alloc((size_t)256 * 4);
  int*   bcur   = (int*)  alloc((size_t)1024 * 4);
  int*   ssrc   = (int*)  alloc((size_t)E * 4);
  float* A      = (float*)alloc((size_t)n * 128 * 4);  // HS1, then HS2
  float* B      = (float*)alloc((size_t)n * 128 * 4);  // x1 (layer-1 output)
  // pairs (12.8 MB) overlays B: only live during CSR build, before B is written
  unsigned long long* pairs = (unsigned long long*)B;

  const int nb = (n + 255) / 256;
  const int nscan = (n + SCHUNK - 1) / SCHUNK;      // 49 blocks (<= 256 required)
  const int NB = (n + (1 << BSHIFT) - 1) >> BSHIFT; // 782 buckets

  // ----- CSR build (once, reused by both layers) -----
  hipMemsetAsync(cnt, 0, (size_t)n * 4, stream);
  count_deg_k<<<2048, 256, 0, stream>>>(ei, E, cnt);
  dinv_k<<<nb, 256, 0, stream>>>(cnt, dinv, n);
  scan1_k<<<nscan, 256, 0, stream>>>(cnt, n, bsum);
  scan2_k<<<1, 256, 0, stream>>>(bsum, nscan, off, n);
  scan3_k<<<nscan, 256, 0, stream>>>(cnt, n, bsum, off, cursor);
  binit_k<<<(NB + 256) / 256, 256, 0, stream>>>(off, bcur, NB, n);
  fill1_k<<<2048, 256, 0, stream>>>(ei, E, bcur, pairs);
  fill2_k<<<NB, 256, 0, stream>>>(off, pairs, cursor, ssrc, n);

  // ----- layer 1 (128 -> 128) -----
  matmul_scale_k<128><<<dim3(1024, 2), 256, 0, stream>>>(x, W1, dinv, A, n);
  aggregate_k<128><<<4096, 256, 0, stream>>>(off, ssrc, A, dinv, b1, B, n);

  // ----- layer 2 (128 -> 64) -----
  matmul_scale_k<64><<<dim3(1024, 1), 256, 0, stream>>>(B, W2, dinv, A, n);
  aggregate_k<64><<<4096, 256, 0, stream>>>(off, ssrc, A, dinv, b2, out, n);
}

// Round 5
// 474.445 us; speedup vs baseline: 1.7996x; 1.7996x over previous
//
#include <hip/hip_runtime.h>

constexpr int IN_DIM = 128;
constexpr int SCHUNK = 2048;  // elements per scan block (256 thr * 8)
constexpr int BSHIFT = 7;     // 128 nodes per bucket
constexpr int G_SORT = 256;   // blocks in the counting-sort passes
// NOTE: requires n <= 2^25 (src packs in 25 bits) and n <= 1024<<BSHIFT (LDS hist); n=100000 ok.

// ---------- degree histogram (edges only; self-loop added analytically) ----------
__global__ void count_deg_k(const int* __restrict__ ei, int E, int* __restrict__ cnt) {
  int i = blockIdx.x * blockDim.x + threadIdx.x;
  int stride = gridDim.x * blockDim.x;
  for (; i < E; i += stride) {
    atomicAdd(&cnt[ei[E + i]], 1);
  }
}

__global__ void dinv_k(const int* __restrict__ cnt, float* __restrict__ dinv, int n) {
  int i = blockIdx.x * blockDim.x + threadIdx.x;
  if (i < n) dinv[i] = rsqrtf((float)cnt[i] + 1.0f);  // +1 self-loop
}

// ---------- hierarchical exclusive scan of cnt[0..n) -> off ----------
__global__ __launch_bounds__(256)
void scan1_k(const int* __restrict__ cnt, int n, int* __restrict__ bsum) {
  __shared__ int sd[256];
  int base = blockIdx.x * SCHUNK + threadIdx.x * 8;
  int s = 0;
#pragma unroll
  for (int j = 0; j < 8; ++j) {
    int i = base + j;
    if (i < n) s += cnt[i];
  }
  sd[threadIdx.x] = s;
  __syncthreads();
  for (int ofs = 128; ofs > 0; ofs >>= 1) {
    if (threadIdx.x < ofs) sd[threadIdx.x] += sd[threadIdx.x + ofs];
    __syncthreads();
  }
  if (threadIdx.x == 0) bsum[blockIdx.x] = sd[0];
}

__global__ __launch_bounds__(256)
void scan2_k(int* __restrict__ bsum, int B, int* __restrict__ off, int n) {
  __shared__ int sd[256];
  int v = (threadIdx.x < B) ? bsum[threadIdx.x] : 0;
  sd[threadIdx.x] = v;
  __syncthreads();
#pragma unroll
  for (int ofs = 1; ofs < 256; ofs <<= 1) {
    int t = (threadIdx.x >= ofs) ? sd[threadIdx.x - ofs] : 0;
    __syncthreads();
    sd[threadIdx.x] += t;
    __syncthreads();
  }
  if (threadIdx.x < B) bsum[threadIdx.x] = sd[threadIdx.x] - v;  // exclusive
  if (threadIdx.x == 255) off[n] = sd[255];                      // total == E
}

__global__ __launch_bounds__(256)
void scan3_k(const int* __restrict__ cnt, int n, const int* __restrict__ bsum,
             int* __restrict__ off) {
  __shared__ int sd[256];
  int base = blockIdx.x * SCHUNK + threadIdx.x * 8;
  int v[8];
  int s = 0;
#pragma unroll
  for (int j = 0; j < 8; ++j) {
    int i = base + j;
    v[j] = (i < n) ? cnt[i] : 0;
    s += v[j];
  }
  sd[threadIdx.x] = s;
  __syncthreads();
#pragma unroll
  for (int ofs = 1; ofs < 256; ofs <<= 1) {
    int t = (threadIdx.x >= ofs) ? sd[threadIdx.x - ofs] : 0;
    __syncthreads();
    sd[threadIdx.x] += t;
    __syncthreads();
  }
  int running = bsum[blockIdx.x] + sd[threadIdx.x] - s;  // exclusive prefix
#pragma unroll
  for (int j = 0; j < 8; ++j) {
    int i = base + j;
    if (i < n) off[i] = running;
    running += v[j];
  }
}

// ---------- contention-free counting sort of edges into buckets ----------
// pass A: per-block LDS histogram over buckets -> hist[g][K]
__global__ __launch_bounds__(256)
void hist_k(const int* __restrict__ ei, int E, int K, int* __restrict__ hist) {
  __shared__ int lh[1024];
  for (int i = threadIdx.x; i < K; i += 256) lh[i] = 0;
  __syncthreads();
  int C = (E + gridDim.x - 1) / gridDim.x;
  int beg = blockIdx.x * C;
  int end = min(E, beg + C);
  for (int i = beg + threadIdx.x; i < end; i += 256)
    atomicAdd(&lh[ei[E + i] >> BSHIFT], 1);
  __syncthreads();
  for (int i = threadIdx.x; i < K; i += 256) hist[blockIdx.x * K + i] = lh[i];
}

// pass B: column-scan hist over blocks + bucket CSR base -> exact write offsets (in place)
// one block per bucket; blockDim == G_SORT
__global__ __launch_bounds__(G_SORT)
void hscan_k(int* __restrict__ hist, int K, const int* __restrict__ off) {
  __shared__ int sd[G_SORT];
  int k = blockIdx.x;
  int v = hist[threadIdx.x * K + k];
  sd[threadIdx.x] = v;
  __syncthreads();
#pragma unroll
  for (int ofs = 1; ofs < G_SORT; ofs <<= 1) {
    int t = (threadIdx.x >= ofs) ? sd[threadIdx.x - ofs] : 0;
    __syncthreads();
    sd[threadIdx.x] += t;
    __syncthreads();
  }
  hist[threadIdx.x * K + k] = off[k << BSHIFT] + sd[threadIdx.x] - v;  // exclusive + base
}

// pass C: re-read chunk, place packed (d_local,src) at reserved positions (LDS cursors)
__global__ __launch_bounds__(256)
void fillc_k(const int* __restrict__ ei, int E, int K, const int* __restrict__ hist,
             unsigned* __restrict__ ent) {
  __shared__ int lcur[1024];
  for (int i = threadIdx.x; i < K; i += 256) lcur[i] = hist[blockIdx.x * K + i];
  __syncthreads();
  int C = (E + gridDim.x - 1) / gridDim.x;
  int beg = blockIdx.x * C;
  int end = min(E, beg + C);
  for (int i = beg + threadIdx.x; i < end; i += 256) {
    int s = ei[i];
    int d = ei[E + i];
    int pos = atomicAdd(&lcur[d >> BSHIFT], 1);
    ent[pos] = ((unsigned)(d & ((1 << BSHIFT) - 1)) << 25) | (unsigned)s;
  }
}

// pass D: per-bucket block -> node-exact CSR (LDS counters only, no global atomics)
__global__ __launch_bounds__(256)
void fill2_k(const int* __restrict__ off, const unsigned* __restrict__ ent,
             int* __restrict__ ssrc, int n) {
  __shared__ int lbase[1 << BSHIFT];
  __shared__ int lcnt[1 << BSHIFT];
  int node0 = blockIdx.x << BSHIFT;
  int node1 = min(node0 + (1 << BSHIFT), n);
  int nn = node1 - node0;
  if (threadIdx.x < nn) {
    lbase[threadIdx.x] = off[node0 + threadIdx.x];
    lcnt[threadIdx.x] = 0;
  }
  __syncthreads();
  int beg = off[node0], end = off[node1];
  for (int i = beg + threadIdx.x; i < end; i += 256) {
    unsigned p = ent[i];
    int dl = (int)(p >> 25);
    int s  = (int)(p & ((1u << 25) - 1));
    int pos = lbase[dl] + atomicAdd(&lcnt[dl], 1);
    ssrc[pos] = s;
  }
}

// ---------- matmul with dinv row-scale epilogue ----------
template<int OUT>
__global__ __launch_bounds__(256)
void matmul_scale_k(const float* __restrict__ X, const float* __restrict__ W,
                    const float* __restrict__ dinv, float* __restrict__ HS, int n) {
  constexpr int COLS = 64;
  constexpr int OG = COLS / 4;     // 16 threads per row
  constexpr int RPP = 256 / OG;    // 16 rows per pass
  __shared__ float Ws[IN_DIM * COLS];  // 32 KB
  __shared__ float XS[RPP * IN_DIM];   // 8 KB
  const int col0 = blockIdx.y * COLS;

  for (int i = threadIdx.x; i < IN_DIM * COLS; i += 256) {
    int k = i / COLS, c = i % COLS;
    Ws[i] = W[k * OUT + col0 + c];
  }

  const int og = threadIdx.x % OG;
  const int r  = threadIdx.x / OG;
  const int o4 = og * 4;

  for (int row0 = blockIdx.x * RPP; row0 < n; row0 += gridDim.x * RPP) {
    __syncthreads();
    for (int i = threadIdx.x; i < RPP * IN_DIM; i += 256) {
      int row = row0 + (i / IN_DIM);
      XS[i] = (row < n) ? X[(long long)row * IN_DIM + (i % IN_DIM)] : 0.0f;
    }
    __syncthreads();

    float4 acc = make_float4(0.f, 0.f, 0.f, 0.f);
#pragma unroll
    for (int k = 0; k < IN_DIM; k += 4) {
      float4 xv = *(const float4*)&XS[r * IN_DIM + k];
      const float* wp = &Ws[k * COLS + o4];
      float4 w0 = *(const float4*)(wp);
      float4 w1 = *(const float4*)(wp + COLS);
      float4 w2 = *(const float4*)(wp + 2 * COLS);
      float4 w3 = *(const float4*)(wp + 3 * COLS);
      acc.x = fmaf(xv.x, w0.x, fmaf(xv.y, w1.x, fmaf(xv.z, w2.x, fmaf(xv.w, w3.x, acc.x))));
      acc.y = fmaf(xv.x, w0.y, fmaf(xv.y, w1.y, fmaf(xv.z, w2.y, fmaf(xv.w, w3.y, acc.y))));
      acc.z = fmaf(xv.x, w0.z, fmaf(xv.y, w1.z, fmaf(xv.z, w2.z, fmaf(xv.w, w3.z, acc.z))));
      acc.w = fmaf(xv.x, w0.w, fmaf(xv.y, w1.w, fmaf(xv.z, w2.w, fmaf(xv.w, w3.w, acc.w))));
    }
    int row = row0 + r;
    if (row < n) {
      float s = dinv[row];
      *(float4*)&HS[(long long)row * OUT + col0 + o4] =
          make_float4(acc.x * s, acc.y * s, acc.z * s, acc.w * s);
    }
  }
}

// ---------- CSR aggregate + fused finalize ----------
template<int OUT>
__global__ __launch_bounds__(256)
void aggregate_k(const int* __restrict__ off, const int* __restrict__ ssrc,
                 const float* __restrict__ HS, const float* __restrict__ dinv,
                 const float* __restrict__ bias, float* __restrict__ Y, int n) {
  constexpr int TPR = OUT / 4;       // lanes per row (32 or 16)
  constexpr int RPB = 256 / TPR;     // rows per block (8 or 16)
  const int lane = threadIdx.x % TPR;
  const int r    = threadIdx.x / TPR;
  const int o4   = lane * 4;
  const float4 bb = *(const float4*)&bias[o4];

  for (int d = blockIdx.x * RPB + r; d < n; d += gridDim.x * RPB) {
    int beg = off[d], end = off[d + 1];
    float4 acc = *(const float4*)&HS[(long long)d * OUT + o4];  // self-loop term
    for (int e = beg; e < end; ++e) {
      int s = ssrc[e];
      float4 v = *(const float4*)&HS[(long long)s * OUT + o4];
      acc.x += v.x; acc.y += v.y; acc.z += v.z; acc.w += v.w;
    }
    float di = dinv[d];
    float4 y;
    y.x = fmaxf(fmaf(di, acc.x, bb.x), 0.f);
    y.y = fmaxf(fmaf(di, acc.y, bb.y), 0.f);
    y.z = fmaxf(fmaf(di, acc.z, bb.z), 0.f);
    y.w = fmaxf(fmaf(di, acc.w, bb.w), 0.f);
    *(float4*)&Y[(long long)d * OUT + o4] = y;
  }
}

extern "C" void kernel_launch(void* const* d_in, const int* in_sizes, int n_in,
                              void* d_out, int out_size, void* d_ws, size_t ws_size,
                              hipStream_t stream) {
  const float* x  = (const float*)d_in[0];
  const int*   ei = (const int*)d_in[1];
  const float* W1 = (const float*)d_in[2];
  const float* b1 = (const float*)d_in[3];
  const float* W2 = (const float*)d_in[4];
  const float* b2 = (const float*)d_in[5];
  float* out = (float*)d_out;

  const int n = in_sizes[0] / IN_DIM;   // 100000
  const int E = in_sizes[1] / 2;        // 1600000

  // workspace layout (bytes)
  char* ws = (char*)d_ws;
  size_t o = 0;
  auto alloc = [&](size_t bytes) { char* p = ws + o; o = (o + bytes + 255) & ~(size_t)255; return p; };
  float* dinv   = (float*)alloc((size_t)n * 4);
  int*   off    = (int*)  alloc((size_t)(n + 1) * 4);
  int*   cnt    = (int*)  alloc((size_t)n * 4);
  int*   bsum   = (int*)  alloc((size_t)256 * 4);
  int*   hist   = (int*)  alloc((size_t)G_SORT * 1024 * 4);  // 1 MB
  int*   ssrc   = (int*)  alloc((size_t)E * 4);
  float* A      = (float*)alloc((size_t)n * 128 * 4);  // HS1, then HS2
  float* B      = (float*)alloc((size_t)n * 128 * 4);  // x1 (layer-1 output)
  // ent (6.4 MB) overlays B: only live during CSR build, before B is written
  unsigned* ent = (unsigned*)B;

  const int nb = (n + 255) / 256;
  const int nscan = (n + SCHUNK - 1) / SCHUNK;      // 49 blocks (<= 256 required)
  const int NB = (n + (1 << BSHIFT) - 1) >> BSHIFT; // 782 buckets (<= 1024 required)

  // ----- CSR build (once, reused by both layers) -----
  hipMemsetAsync(cnt, 0, (size_t)n * 4, stream);
  count_deg_k<<<2048, 256, 0, stream>>>(ei, E, cnt);
  dinv_k<<<nb, 256, 0, stream>>>(cnt, dinv, n);
  scan1_k<<<nscan, 256, 0, stream>>>(cnt, n, bsum);
  scan2_k<<<1, 256, 0, stream>>>(bsum, nscan, off, n);
  scan3_k<<<nscan, 256, 0, stream>>>(cnt, n, bsum, off);
  hist_k<<<G_SORT, 256, 0, stream>>>(ei, E, NB, hist);
  hscan_k<<<NB, G_SORT, 0, stream>>>(hist, NB, off);
  fillc_k<<<G_SORT, 256, 0, stream>>>(ei, E, NB, hist, ent);
  fill2_k<<<NB, 256, 0, stream>>>(off, ent, ssrc, n);

  // ----- layer 1 (128 -> 128) -----
  matmul_scale_k<128><<<dim3(1024, 2), 256, 0, stream>>>(x, W1, dinv, A, n);
  aggregate_k<128><<<4096, 256, 0, stream>>>(off, ssrc, A, dinv, b1, B, n);

  // ----- layer 2 (128 -> 64) -----
  matmul_scale_k<64><<<dim3(1024, 1), 256, 0, stream>>>(B, W2, dinv, A, n);
  aggregate_k<64><<<4096, 256, 0, stream>>>(off, ssrc, A, dinv, b2, out, n);
}

// Round 6
// 454.058 us; speedup vs baseline: 1.8804x; 1.0449x over previous
//
#include <hip/hip_runtime.h>

constexpr int IN_DIM = 128;
constexpr int SCHUNK = 2048;  // elements per scan block (256 thr * 8)
constexpr int BSHIFT = 7;     // 128 nodes per bucket
constexpr int G_SORT = 256;   // blocks in the counting-sort passes
// NOTE: requires n <= 2^25 (src packs in 25 bits) and n <= 1024<<BSHIFT (LDS hist); n=100000 ok.

// ---------- degree histogram (edges only; self-loop added analytically) ----------
__global__ void count_deg_k(const int* __restrict__ ei, int E, int* __restrict__ cnt) {
  int i = blockIdx.x * blockDim.x + threadIdx.x;
  int stride = gridDim.x * blockDim.x;
  for (; i < E; i += stride) {
    atomicAdd(&cnt[ei[E + i]], 1);
  }
}

__global__ void dinv_k(const int* __restrict__ cnt, float* __restrict__ dinv, int n) {
  int i = blockIdx.x * blockDim.x + threadIdx.x;
  if (i < n) dinv[i] = rsqrtf((float)cnt[i] + 1.0f);  // +1 self-loop
}

// ---------- hierarchical exclusive scan of cnt[0..n) -> off ----------
__global__ __launch_bounds__(256)
void scan1_k(const int* __restrict__ cnt, int n, int* __restrict__ bsum) {
  __shared__ int sd[256];
  int base = blockIdx.x * SCHUNK + threadIdx.x * 8;
  int s = 0;
#pragma unroll
  for (int j = 0; j < 8; ++j) {
    int i = base + j;
    if (i < n) s += cnt[i];
  }
  sd[threadIdx.x] = s;
  __syncthreads();
  for (int ofs = 128; ofs > 0; ofs >>= 1) {
    if (threadIdx.x < ofs) sd[threadIdx.x] += sd[threadIdx.x + ofs];
    __syncthreads();
  }
  if (threadIdx.x == 0) bsum[blockIdx.x] = sd[0];
}

__global__ __launch_bounds__(256)
void scan2_k(int* __restrict__ bsum, int B, int* __restrict__ off, int n) {
  __shared__ int sd[256];
  int v = (threadIdx.x < B) ? bsum[threadIdx.x] : 0;
  sd[threadIdx.x] = v;
  __syncthreads();
#pragma unroll
  for (int ofs = 1; ofs < 256; ofs <<= 1) {
    int t = (threadIdx.x >= ofs) ? sd[threadIdx.x - ofs] : 0;
    __syncthreads();
    sd[threadIdx.x] += t;
    __syncthreads();
  }
  if (threadIdx.x < B) bsum[threadIdx.x] = sd[threadIdx.x] - v;  // exclusive
  if (threadIdx.x == 255) off[n] = sd[255];                      // total == E
}

__global__ __launch_bounds__(256)
void scan3_k(const int* __restrict__ cnt, int n, const int* __restrict__ bsum,
             int* __restrict__ off) {
  __shared__ int sd[256];
  int base = blockIdx.x * SCHUNK + threadIdx.x * 8;
  int v[8];
  int s = 0;
#pragma unroll
  for (int j = 0; j < 8; ++j) {
    int i = base + j;
    v[j] = (i < n) ? cnt[i] : 0;
    s += v[j];
  }
  sd[threadIdx.x] = s;
  __syncthreads();
#pragma unroll
  for (int ofs = 1; ofs < 256; ofs <<= 1) {
    int t = (threadIdx.x >= ofs) ? sd[threadIdx.x - ofs] : 0;
    __syncthreads();
    sd[threadIdx.x] += t;
    __syncthreads();
  }
  int running = bsum[blockIdx.x] + sd[threadIdx.x] - s;  // exclusive prefix
#pragma unroll
  for (int j = 0; j < 8; ++j) {
    int i = base + j;
    if (i < n) off[i] = running;
    running += v[j];
  }
}

// ---------- contention-free counting sort of edges into buckets ----------
__global__ __launch_bounds__(256)
void hist_k(const int* __restrict__ ei, int E, int K, int* __restrict__ hist) {
  __shared__ int lh[1024];
  for (int i = threadIdx.x; i < K; i += 256) lh[i] = 0;
  __syncthreads();
  int C = (E + gridDim.x - 1) / gridDim.x;
  int beg = blockIdx.x * C;
  int end = min(E, beg + C);
  for (int i = beg + threadIdx.x; i < end; i += 256)
    atomicAdd(&lh[ei[E + i] >> BSHIFT], 1);
  __syncthreads();
  for (int i = threadIdx.x; i < K; i += 256) hist[blockIdx.x * K + i] = lh[i];
}

__global__ __launch_bounds__(G_SORT)
void hscan_k(int* __restrict__ hist, int K, const int* __restrict__ off) {
  __shared__ int sd[G_SORT];
  int k = blockIdx.x;
  int v = hist[threadIdx.x * K + k];
  sd[threadIdx.x] = v;
  __syncthreads();
#pragma unroll
  for (int ofs = 1; ofs < G_SORT; ofs <<= 1) {
    int t = (threadIdx.x >= ofs) ? sd[threadIdx.x - ofs] : 0;
    __syncthreads();
    sd[threadIdx.x] += t;
    __syncthreads();
  }
  hist[threadIdx.x * K + k] = off[k << BSHIFT] + sd[threadIdx.x] - v;  // exclusive + base
}

__global__ __launch_bounds__(256)
void fillc_k(const int* __restrict__ ei, int E, int K, const int* __restrict__ hist,
             unsigned* __restrict__ ent) {
  __shared__ int lcur[1024];
  for (int i = threadIdx.x; i < K; i += 256) lcur[i] = hist[blockIdx.x * K + i];
  __syncthreads();
  int C = (E + gridDim.x - 1) / gridDim.x;
  int beg = blockIdx.x * C;
  int end = min(E, beg + C);
  for (int i = beg + threadIdx.x; i < end; i += 256) {
    int s = ei[i];
    int d = ei[E + i];
    int pos = atomicAdd(&lcur[d >> BSHIFT], 1);
    ent[pos] = ((unsigned)(d & ((1 << BSHIFT) - 1)) << 25) | (unsigned)s;
  }
}

__global__ __launch_bounds__(256)
void fill2_k(const int* __restrict__ off, const unsigned* __restrict__ ent,
             int* __restrict__ ssrc, int n) {
  __shared__ int lbase[1 << BSHIFT];
  __shared__ int lcnt[1 << BSHIFT];
  int node0 = blockIdx.x << BSHIFT;
  int node1 = min(node0 + (1 << BSHIFT), n);
  int nn = node1 - node0;
  if (threadIdx.x < nn) {
    lbase[threadIdx.x] = off[node0 + threadIdx.x];
    lcnt[threadIdx.x] = 0;
  }
  __syncthreads();
  int beg = off[node0], end = off[node1];
  for (int i = beg + threadIdx.x; i < end; i += 256) {
    unsigned p = ent[i];
    int dl = (int)(p >> 25);
    int s  = (int)(p & ((1u << 25) - 1));
    int pos = lbase[dl] + atomicAdd(&lcnt[dl], 1);
    ssrc[pos] = s;
  }
}

// ---------- matmul with dinv row-scale epilogue ----------
template<int OUT>
__global__ __launch_bounds__(256)
void matmul_scale_k(const float* __restrict__ X, const float* __restrict__ W,
                    const float* __restrict__ dinv, float* __restrict__ HS, int n) {
  constexpr int COLS = 64;
  constexpr int OG = COLS / 4;     // 16 threads per row
  constexpr int RPP = 256 / OG;    // 16 rows per pass
  __shared__ float Ws[IN_DIM * COLS];  // 32 KB
  __shared__ float XS[RPP * IN_DIM];   // 8 KB
  const int col0 = blockIdx.y * COLS;

  for (int i = threadIdx.x; i < IN_DIM * COLS; i += 256) {
    int k = i / COLS, c = i % COLS;
    Ws[i] = W[k * OUT + col0 + c];
  }

  const int og = threadIdx.x % OG;
  const int r  = threadIdx.x / OG;
  const int o4 = og * 4;

  for (int row0 = blockIdx.x * RPP; row0 < n; row0 += gridDim.x * RPP) {
    __syncthreads();
    for (int i = threadIdx.x; i < RPP * IN_DIM; i += 256) {
      int row = row0 + (i / IN_DIM);
      XS[i] = (row < n) ? X[(long long)row * IN_DIM + (i % IN_DIM)] : 0.0f;
    }
    __syncthreads();

    float4 acc = make_float4(0.f, 0.f, 0.f, 0.f);
#pragma unroll
    for (int k = 0; k < IN_DIM; k += 4) {
      float4 xv = *(const float4*)&XS[r * IN_DIM + k];
      const float* wp = &Ws[k * COLS + o4];
      float4 w0 = *(const float4*)(wp);
      float4 w1 = *(const float4*)(wp + COLS);
      float4 w2 = *(const float4*)(wp + 2 * COLS);
      float4 w3 = *(const float4*)(wp + 3 * COLS);
      acc.x = fmaf(xv.x, w0.x, fmaf(xv.y, w1.x, fmaf(xv.z, w2.x, fmaf(xv.w, w3.x, acc.x))));
      acc.y = fmaf(xv.x, w0.y, fmaf(xv.y, w1.y, fmaf(xv.z, w2.y, fmaf(xv.w, w3.y, acc.y))));
      acc.z = fmaf(xv.x, w0.z, fmaf(xv.y, w1.z, fmaf(xv.z, w2.z, fmaf(xv.w, w3.z, acc.z))));
      acc.w = fmaf(xv.x, w0.w, fmaf(xv.y, w1.w, fmaf(xv.z, w2.w, fmaf(xv.w, w3.w, acc.w))));
    }
    int row = row0 + r;
    if (row < n) {
      float s = dinv[row];
      *(float4*)&HS[(long long)row * OUT + col0 + o4] =
          make_float4(acc.x * s, acc.y * s, acc.z * s, acc.w * s);
    }
  }
}

// ---------- CSR aggregate + fused finalize, 4x-unrolled gathers for MLP ----------
template<int OUT>
__global__ __launch_bounds__(256)
void aggregate_k(const int* __restrict__ off, const int* __restrict__ ssrc,
                 const float* __restrict__ HS, const float* __restrict__ dinv,
                 const float* __restrict__ bias, float* __restrict__ Y, int n) {
  constexpr int TPR = OUT / 4;       // lanes per row (32 or 16)
  constexpr int RPB = 256 / TPR;     // rows per block (8 or 16)
  const int lane = threadIdx.x % TPR;
  const int r    = threadIdx.x / TPR;
  const int o4   = lane * 4;
  const float4 bb = *(const float4*)&bias[o4];

  for (int d = blockIdx.x * RPB + r; d < n; d += gridDim.x * RPB) {
    int beg = off[d], end = off[d + 1];
    float4 acc = *(const float4*)&HS[(long long)d * OUT + o4];  // self-loop term
    int e = beg;
    // 4 independent gathers in flight per lane (latency hiding)
    for (; e + 4 <= end; e += 4) {
      int s0 = ssrc[e], s1 = ssrc[e + 1], s2 = ssrc[e + 2], s3 = ssrc[e + 3];
      float4 v0 = *(const float4*)&HS[(long long)s0 * OUT + o4];
      float4 v1 = *(const float4*)&HS[(long long)s1 * OUT + o4];
      float4 v2 = *(const float4*)&HS[(long long)s2 * OUT + o4];
      float4 v3 = *(const float4*)&HS[(long long)s3 * OUT + o4];
      acc.x += (v0.x + v1.x) + (v2.x + v3.x);
      acc.y += (v0.y + v1.y) + (v2.y + v3.y);
      acc.z += (v0.z + v1.z) + (v2.z + v3.z);
      acc.w += (v0.w + v1.w) + (v2.w + v3.w);
    }
    for (; e < end; ++e) {
      int s = ssrc[e];
      float4 v = *(const float4*)&HS[(long long)s * OUT + o4];
      acc.x += v.x; acc.y += v.y; acc.z += v.z; acc.w += v.w;
    }
    float di = dinv[d];
    float4 y;
    y.x = fmaxf(fmaf(di, acc.x, bb.x), 0.f);
    y.y = fmaxf(fmaf(di, acc.y, bb.y), 0.f);
    y.z = fmaxf(fmaf(di, acc.z, bb.z), 0.f);
    y.w = fmaxf(fmaf(di, acc.w, bb.w), 0.f);
    *(float4*)&Y[(long long)d * OUT + o4] = y;
  }
}

extern "C" void kernel_launch(void* const* d_in, const int* in_sizes, int n_in,
                              void* d_out, int out_size, void* d_ws, size_t ws_size,
                              hipStream_t stream) {
  const float* x  = (const float*)d_in[0];
  const int*   ei = (const int*)d_in[1];
  const float* W1 = (const float*)d_in[2];
  const float* b1 = (const float*)d_in[3];
  const float* W2 = (const float*)d_in[4];
  const float* b2 = (const float*)d_in[5];
  float* out = (float*)d_out;

  const int n = in_sizes[0] / IN_DIM;   // 100000
  const int E = in_sizes[1] / 2;        // 1600000

  // workspace layout (bytes)
  char* ws = (char*)d_ws;
  size_t o = 0;
  auto alloc = [&](size_t bytes) { char* p = ws + o; o = (o + bytes + 255) & ~(size_t)255; return p; };
  float* dinv   = (float*)alloc((size_t)n * 4);
  int*   off    = (int*)  alloc((size_t)(n + 1) * 4);
  int*   cnt    = (int*)  alloc((size_t)n * 4);
  int*   bsum   = (int*)  alloc((size_t)256 * 4);
  int*   hist   = (int*)  alloc((size_t)G_SORT * 1024 * 4);  // 1 MB
  int*   ssrc   = (int*)  alloc((size_t)E * 4);
  float* A      = (float*)alloc((size_t)n * 128 * 4);  // HS1, then HS2
  float* B      = (float*)alloc((size_t)n * 128 * 4);  // x1 (layer-1 output)
  // ent (6.4 MB) overlays B: only live during CSR build, before B is written
  unsigned* ent = (unsigned*)B;

  const int nb = (n + 255) / 256;
  const int nscan = (n + SCHUNK - 1) / SCHUNK;      // 49 blocks (<= 256 required)
  const int NB = (n + (1 << BSHIFT) - 1) >> BSHIFT; // 782 buckets (<= 1024 required)

  // ----- CSR build (once, reused by both layers) -----
  hipMemsetAsync(cnt, 0, (size_t)n * 4, stream);
  count_deg_k<<<2048, 256, 0, stream>>>(ei, E, cnt);
  dinv_k<<<nb, 256, 0, stream>>>(cnt, dinv, n);
  scan1_k<<<nscan, 256, 0, stream>>>(cnt, n, bsum);
  scan2_k<<<1, 256, 0, stream>>>(bsum, nscan, off, n);
  scan3_k<<<nscan, 256, 0, stream>>>(cnt, n, bsum, off);
  hist_k<<<G_SORT, 256, 0, stream>>>(ei, E, NB, hist);
  hscan_k<<<NB, G_SORT, 0, stream>>>(hist, NB, off);
  fillc_k<<<G_SORT, 256, 0, stream>>>(ei, E, NB, hist, ent);
  fill2_k<<<NB, 256, 0, stream>>>(off, ent, ssrc, n);

  // ----- layer 1 (128 -> 128) -----
  matmul_scale_k<128><<<dim3(1024, 2), 256, 0, stream>>>(x, W1, dinv, A, n);
  aggregate_k<128><<<4096, 256, 0, stream>>>(off, ssrc, A, dinv, b1, B, n);

  // ----- layer 2 (128 -> 64) -----
  matmul_scale_k<64><<<dim3(1024, 1), 256, 0, stream>>>(B, W2, dinv, A, n);
  aggregate_k<64><<<4096, 256, 0, stream>>>(off, ssrc, A, dinv, b2, out, n);
}

// Round 7
// 425.406 us; speedup vs baseline: 2.0071x; 1.0674x over previous
//
#include <hip/hip_runtime.h>

constexpr int IN_DIM = 128;
constexpr int SCHUNK = 2048;  // elements per scan block (256 thr * 8)
constexpr int BSHIFT = 7;     // 128 nodes per bucket
constexpr int G_SORT = 256;   // blocks in the counting-sort passes
// NOTE: requires n <= 2^25 (src packs in 25 bits) and n <= 1024<<BSHIFT (LDS hist); n=100000 ok.

// bf16 helpers: storage-only compression of HS (accumulate in fp32)
__device__ inline unsigned pk_bf16(float a, float b) {  // RTNE pack of 2 floats
  unsigned ua = __float_as_uint(a), ub = __float_as_uint(b);
  ua += 0x7fff + ((ua >> 16) & 1);
  ub += 0x7fff + ((ub >> 16) & 1);
  return (ua >> 16) | (ub & 0xffff0000u);
}
__device__ inline float bf_lo(unsigned u) { return __uint_as_float(u << 16); }
__device__ inline float bf_hi(unsigned u) { return __uint_as_float(u & 0xffff0000u); }

// ---------- degree histogram (edges only; self-loop added analytically) ----------
__global__ void count_deg_k(const int* __restrict__ ei, int E, int* __restrict__ cnt) {
  int i = blockIdx.x * blockDim.x + threadIdx.x;
  int stride = gridDim.x * blockDim.x;
  for (; i < E; i += stride) {
    atomicAdd(&cnt[ei[E + i]], 1);
  }
}

__global__ void dinv_k(const int* __restrict__ cnt, float* __restrict__ dinv, int n) {
  int i = blockIdx.x * blockDim.x + threadIdx.x;
  if (i < n) dinv[i] = rsqrtf((float)cnt[i] + 1.0f);  // +1 self-loop
}

// ---------- hierarchical exclusive scan of cnt[0..n) -> off ----------
__global__ __launch_bounds__(256)
void scan1_k(const int* __restrict__ cnt, int n, int* __restrict__ bsum) {
  __shared__ int sd[256];
  int base = blockIdx.x * SCHUNK + threadIdx.x * 8;
  int s = 0;
#pragma unroll
  for (int j = 0; j < 8; ++j) {
    int i = base + j;
    if (i < n) s += cnt[i];
  }
  sd[threadIdx.x] = s;
  __syncthreads();
  for (int ofs = 128; ofs > 0; ofs >>= 1) {
    if (threadIdx.x < ofs) sd[threadIdx.x] += sd[threadIdx.x + ofs];
    __syncthreads();
  }
  if (threadIdx.x == 0) bsum[blockIdx.x] = sd[0];
}

__global__ __launch_bounds__(256)
void scan2_k(int* __restrict__ bsum, int B, int* __restrict__ off, int n) {
  __shared__ int sd[256];
  int v = (threadIdx.x < B) ? bsum[threadIdx.x] : 0;
  sd[threadIdx.x] = v;
  __syncthreads();
#pragma unroll
  for (int ofs = 1; ofs < 256; ofs <<= 1) {
    int t = (threadIdx.x >= ofs) ? sd[threadIdx.x - ofs] : 0;
    __syncthreads();
    sd[threadIdx.x] += t;
    __syncthreads();
  }
  if (threadIdx.x < B) bsum[threadIdx.x] = sd[threadIdx.x] - v;  // exclusive
  if (threadIdx.x == 255) off[n] = sd[255];                      // total == E
}

__global__ __launch_bounds__(256)
void scan3_k(const int* __restrict__ cnt, int n, const int* __restrict__ bsum,
             int* __restrict__ off) {
  __shared__ int sd[256];
  int base = blockIdx.x * SCHUNK + threadIdx.x * 8;
  int v[8];
  int s = 0;
#pragma unroll
  for (int j = 0; j < 8; ++j) {
    int i = base + j;
    v[j] = (i < n) ? cnt[i] : 0;
    s += v[j];
  }
  sd[threadIdx.x] = s;
  __syncthreads();
#pragma unroll
  for (int ofs = 1; ofs < 256; ofs <<= 1) {
    int t = (threadIdx.x >= ofs) ? sd[threadIdx.x - ofs] : 0;
    __syncthreads();
    sd[threadIdx.x] += t;
    __syncthreads();
  }
  int running = bsum[blockIdx.x] + sd[threadIdx.x] - s;  // exclusive prefix
#pragma unroll
  for (int j = 0; j < 8; ++j) {
    int i = base + j;
    if (i < n) off[i] = running;
    running += v[j];
  }
}

// ---------- contention-free counting sort of edges into buckets ----------
__global__ __launch_bounds__(256)
void hist_k(const int* __restrict__ ei, int E, int K, int* __restrict__ hist) {
  __shared__ int lh[1024];
  for (int i = threadIdx.x; i < K; i += 256) lh[i] = 0;
  __syncthreads();
  int C = (E + gridDim.x - 1) / gridDim.x;
  int beg = blockIdx.x * C;
  int end = min(E, beg + C);
  for (int i = beg + threadIdx.x; i < end; i += 256)
    atomicAdd(&lh[ei[E + i] >> BSHIFT], 1);
  __syncthreads();
  for (int i = threadIdx.x; i < K; i += 256) hist[blockIdx.x * K + i] = lh[i];
}

__global__ __launch_bounds__(G_SORT)
void hscan_k(int* __restrict__ hist, int K, const int* __restrict__ off) {
  __shared__ int sd[G_SORT];
  int k = blockIdx.x;
  int v = hist[threadIdx.x * K + k];
  sd[threadIdx.x] = v;
  __syncthreads();
#pragma unroll
  for (int ofs = 1; ofs < G_SORT; ofs <<= 1) {
    int t = (threadIdx.x >= ofs) ? sd[threadIdx.x - ofs] : 0;
    __syncthreads();
    sd[threadIdx.x] += t;
    __syncthreads();
  }
  hist[threadIdx.x * K + k] = off[k << BSHIFT] + sd[threadIdx.x] - v;  // exclusive + base
}

__global__ __launch_bounds__(256)
void fillc_k(const int* __restrict__ ei, int E, int K, const int* __restrict__ hist,
             unsigned* __restrict__ ent) {
  __shared__ int lcur[1024];
  for (int i = threadIdx.x; i < K; i += 256) lcur[i] = hist[blockIdx.x * K + i];
  __syncthreads();
  int C = (E + gridDim.x - 1) / gridDim.x;
  int beg = blockIdx.x * C;
  int end = min(E, beg + C);
  for (int i = beg + threadIdx.x; i < end; i += 256) {
    int s = ei[i];
    int d = ei[E + i];
    int pos = atomicAdd(&lcur[d >> BSHIFT], 1);
    ent[pos] = ((unsigned)(d & ((1 << BSHIFT) - 1)) << 25) | (unsigned)s;
  }
}

__global__ __launch_bounds__(256)
void fill2_k(const int* __restrict__ off, const unsigned* __restrict__ ent,
             int* __restrict__ ssrc, int n) {
  __shared__ int lbase[1 << BSHIFT];
  __shared__ int lcnt[1 << BSHIFT];
  int node0 = blockIdx.x << BSHIFT;
  int node1 = min(node0 + (1 << BSHIFT), n);
  int nn = node1 - node0;
  if (threadIdx.x < nn) {
    lbase[threadIdx.x] = off[node0 + threadIdx.x];
    lcnt[threadIdx.x] = 0;
  }
  __syncthreads();
  int beg = off[node0], end = off[node1];
  for (int i = beg + threadIdx.x; i < end; i += 256) {
    unsigned p = ent[i];
    int dl = (int)(p >> 25);
    int s  = (int)(p & ((1u << 25) - 1));
    int pos = lbase[dl] + atomicAdd(&lcnt[dl], 1);
    ssrc[pos] = s;
  }
}

// ---------- matmul with dinv row-scale epilogue; bf16 packed output ----------
// HSb[row][c] (bf16) = dinv[row] * sum_k X[row][k] * W[k][c]
template<int OUT>
__global__ __launch_bounds__(256)
void matmul_scale_k(const float* __restrict__ X, const float* __restrict__ W,
                    const float* __restrict__ dinv, unsigned* __restrict__ HSb, int n) {
  constexpr int COLS = 64;
  constexpr int OG = COLS / 4;     // 16 threads per row
  constexpr int RPP = 256 / OG;    // 16 rows per pass
  __shared__ float Ws[IN_DIM * COLS];  // 32 KB
  __shared__ float XS[RPP * IN_DIM];   // 8 KB
  const int col0 = blockIdx.y * COLS;

  for (int i = threadIdx.x; i < IN_DIM * COLS; i += 256) {
    int k = i / COLS, c = i % COLS;
    Ws[i] = W[k * OUT + col0 + c];
  }

  const int og = threadIdx.x % OG;
  const int r  = threadIdx.x / OG;
  const int o4 = og * 4;

  for (int row0 = blockIdx.x * RPP; row0 < n; row0 += gridDim.x * RPP) {
    __syncthreads();
    for (int i = threadIdx.x; i < RPP * IN_DIM; i += 256) {
      int row = row0 + (i / IN_DIM);
      XS[i] = (row < n) ? X[(long long)row * IN_DIM + (i % IN_DIM)] : 0.0f;
    }
    __syncthreads();

    float4 acc = make_float4(0.f, 0.f, 0.f, 0.f);
#pragma unroll
    for (int k = 0; k < IN_DIM; k += 4) {
      float4 xv = *(const float4*)&XS[r * IN_DIM + k];
      const float* wp = &Ws[k * COLS + o4];
      float4 w0 = *(const float4*)(wp);
      float4 w1 = *(const float4*)(wp + COLS);
      float4 w2 = *(const float4*)(wp + 2 * COLS);
      float4 w3 = *(const float4*)(wp + 3 * COLS);
      acc.x = fmaf(xv.x, w0.x, fmaf(xv.y, w1.x, fmaf(xv.z, w2.x, fmaf(xv.w, w3.x, acc.x))));
      acc.y = fmaf(xv.x, w0.y, fmaf(xv.y, w1.y, fmaf(xv.z, w2.y, fmaf(xv.w, w3.y, acc.y))));
      acc.z = fmaf(xv.x, w0.z, fmaf(xv.y, w1.z, fmaf(xv.z, w2.z, fmaf(xv.w, w3.z, acc.z))));
      acc.w = fmaf(xv.x, w0.w, fmaf(xv.y, w1.w, fmaf(xv.z, w2.w, fmaf(xv.w, w3.w, acc.w))));
    }
    int row = row0 + r;
    if (row < n) {
      float s = dinv[row];
      uint2 pv;
      pv.x = pk_bf16(acc.x * s, acc.y * s);
      pv.y = pk_bf16(acc.z * s, acc.w * s);
      *(uint2*)&HSb[(long long)row * (OUT / 2) + (col0 + o4) / 2] = pv;
    }
  }
}

// ---------- CSR aggregate (bf16 gathers, fp32 accumulate) + fused finalize ----------
// Y[d] = relu(dinv[d] * (HS[d] + sum_e HS[ssrc[e]]) + bias)   -- HS stored bf16
template<int OUT>
__global__ __launch_bounds__(256)
void aggregate_k(const int* __restrict__ off, const int* __restrict__ ssrc,
                 const uint4* __restrict__ HSv, const float* __restrict__ dinv,
                 const float* __restrict__ bias, float* __restrict__ Y, int n) {
  constexpr int TPR = OUT / 8;       // lanes per row: 16 (OUT=128) / 8 (OUT=64); 16B per lane
  constexpr int RPB = 256 / TPR;     // rows per block
  const int lane = threadIdx.x % TPR;
  const int r    = threadIdx.x / TPR;
  const int c8   = lane * 8;
  const float4 bb0 = *(const float4*)&bias[c8];
  const float4 bb1 = *(const float4*)&bias[c8 + 4];

  for (int d = blockIdx.x * RPB + r; d < n; d += gridDim.x * RPB) {
    int beg = off[d], end = off[d + 1];
    float acc[8];
    {
      uint4 g = HSv[(long long)d * TPR + lane];  // self-loop term
      acc[0] = bf_lo(g.x); acc[1] = bf_hi(g.x);
      acc[2] = bf_lo(g.y); acc[3] = bf_hi(g.y);
      acc[4] = bf_lo(g.z); acc[5] = bf_hi(g.z);
      acc[6] = bf_lo(g.w); acc[7] = bf_hi(g.w);
    }
    int e = beg;
    for (; e + 4 <= end; e += 4) {  // 4 independent gathers in flight
      int s0 = ssrc[e], s1 = ssrc[e + 1], s2 = ssrc[e + 2], s3 = ssrc[e + 3];
      uint4 g0 = HSv[(long long)s0 * TPR + lane];
      uint4 g1 = HSv[(long long)s1 * TPR + lane];
      uint4 g2 = HSv[(long long)s2 * TPR + lane];
      uint4 g3 = HSv[(long long)s3 * TPR + lane];
      acc[0] += (bf_lo(g0.x) + bf_lo(g1.x)) + (bf_lo(g2.x) + bf_lo(g3.x));
      acc[1] += (bf_hi(g0.x) + bf_hi(g1.x)) + (bf_hi(g2.x) + bf_hi(g3.x));
      acc[2] += (bf_lo(g0.y) + bf_lo(g1.y)) + (bf_lo(g2.y) + bf_lo(g3.y));
      acc[3] += (bf_hi(g0.y) + bf_hi(g1.y)) + (bf_hi(g2.y) + bf_hi(g3.y));
      acc[4] += (bf_lo(g0.z) + bf_lo(g1.z)) + (bf_lo(g2.z) + bf_lo(g3.z));
      acc[5] += (bf_hi(g0.z) + bf_hi(g1.z)) + (bf_hi(g2.z) + bf_hi(g3.z));
      acc[6] += (bf_lo(g0.w) + bf_lo(g1.w)) + (bf_lo(g2.w) + bf_lo(g3.w));
      acc[7] += (bf_hi(g0.w) + bf_hi(g1.w)) + (bf_hi(g2.w) + bf_hi(g3.w));
    }
    for (; e < end; ++e) {
      uint4 g = HSv[(long long)ssrc[e] * TPR + lane];
      acc[0] += bf_lo(g.x); acc[1] += bf_hi(g.x);
      acc[2] += bf_lo(g.y); acc[3] += bf_hi(g.y);
      acc[4] += bf_lo(g.z); acc[5] += bf_hi(g.z);
      acc[6] += bf_lo(g.w); acc[7] += bf_hi(g.w);
    }
    float di = dinv[d];
    float4 y0, y1;
    y0.x = fmaxf(fmaf(di, acc[0], bb0.x), 0.f);
    y0.y = fmaxf(fmaf(di, acc[1], bb0.y), 0.f);
    y0.z = fmaxf(fmaf(di, acc[2], bb0.z), 0.f);
    y0.w = fmaxf(fmaf(di, acc[3], bb0.w), 0.f);
    y1.x = fmaxf(fmaf(di, acc[4], bb1.x), 0.f);
    y1.y = fmaxf(fmaf(di, acc[5], bb1.y), 0.f);
    y1.z = fmaxf(fmaf(di, acc[6], bb1.z), 0.f);
    y1.w = fmaxf(fmaf(di, acc[7], bb1.w), 0.f);
    *(float4*)&Y[(long long)d * OUT + c8] = y0;
    *(float4*)&Y[(long long)d * OUT + c8 + 4] = y1;
  }
}

extern "C" void kernel_launch(void* const* d_in, const int* in_sizes, int n_in,
                              void* d_out, int out_size, void* d_ws, size_t ws_size,
                              hipStream_t stream) {
  const float* x  = (const float*)d_in[0];
  const int*   ei = (const int*)d_in[1];
  const float* W1 = (const float*)d_in[2];
  const float* b1 = (const float*)d_in[3];
  const float* W2 = (const float*)d_in[4];
  const float* b2 = (const float*)d_in[5];
  float* out = (float*)d_out;

  const int n = in_sizes[0] / IN_DIM;   // 100000
  const int E = in_sizes[1] / 2;        // 1600000

  // workspace layout (bytes)
  char* ws = (char*)d_ws;
  size_t o = 0;
  auto alloc = [&](size_t bytes) { char* p = ws + o; o = (o + bytes + 255) & ~(size_t)255; return p; };
  float* dinv   = (float*)alloc((size_t)n * 4);
  int*   off    = (int*)  alloc((size_t)(n + 1) * 4);
  int*   cnt    = (int*)  alloc((size_t)n * 4);
  int*   bsum   = (int*)  alloc((size_t)256 * 4);
  int*   hist   = (int*)  alloc((size_t)G_SORT * 1024 * 4);  // 1 MB
  int*   ssrc   = (int*)  alloc((size_t)E * 4);
  unsigned* A   = (unsigned*)alloc((size_t)n * 128 * 2);  // bf16 HS1 (25.6MB), then bf16 HS2
  float* B      = (float*)alloc((size_t)n * 128 * 4);     // fp32 x1 (layer-1 output)
  // ent (6.4 MB) overlays B: only live during CSR build, before B is written
  unsigned* ent = (unsigned*)B;

  const int nb = (n + 255) / 256;
  const int nscan = (n + SCHUNK - 1) / SCHUNK;      // 49 blocks (<= 256 required)
  const int NB = (n + (1 << BSHIFT) - 1) >> BSHIFT; // 782 buckets (<= 1024 required)

  // ----- CSR build (once, reused by both layers) -----
  hipMemsetAsync(cnt, 0, (size_t)n * 4, stream);
  count_deg_k<<<2048, 256, 0, stream>>>(ei, E, cnt);
  dinv_k<<<nb, 256, 0, stream>>>(cnt, dinv, n);
  scan1_k<<<nscan, 256, 0, stream>>>(cnt, n, bsum);
  scan2_k<<<1, 256, 0, stream>>>(bsum, nscan, off, n);
  scan3_k<<<nscan, 256, 0, stream>>>(cnt, n, bsum, off);
  hist_k<<<G_SORT, 256, 0, stream>>>(ei, E, NB, hist);
  hscan_k<<<NB, G_SORT, 0, stream>>>(hist, NB, off);
  fillc_k<<<G_SORT, 256, 0, stream>>>(ei, E, NB, hist, ent);
  fill2_k<<<NB, 256, 0, stream>>>(off, ent, ssrc, n);

  // ----- layer 1 (128 -> 128) -----
  matmul_scale_k<128><<<dim3(1024, 2), 256, 0, stream>>>(x, W1, dinv, A, n);
  aggregate_k<128><<<4096, 256, 0, stream>>>(off, ssrc, (const uint4*)A, dinv, b1, B, n);

  // ----- layer 2 (128 -> 64) -----
  matmul_scale_k<64><<<dim3(1024, 1), 256, 0, stream>>>(B, W2, dinv, A, n);
  aggregate_k<64><<<4096, 256, 0, stream>>>(off, ssrc, (const uint4*)A, dinv, b2, out, n);
}

// Round 8
// 266.208 us; speedup vs baseline: 3.2073x; 1.5980x over previous
//
#include <hip/hip_runtime.h>

constexpr int IN_DIM = 128;
constexpr int SCHUNK = 2048;  // elements per scan block (256 thr * 8)
constexpr int BSHIFT = 7;     // 128 nodes per bucket
constexpr int G_SORT = 256;   // blocks in the counting-sort passes
// NOTE: requires n <= 2^25 (src packs in 25 bits) and n <= 1024<<BSHIFT (LDS hist); n=100000 ok.

typedef float  f32x4  __attribute__((ext_vector_type(4)));
typedef short  bf16x8 __attribute__((ext_vector_type(8)));

// bf16 helpers: storage-only compression (accumulate in fp32)
__device__ inline unsigned pk_bf16(float a, float b) {  // RTNE pack of 2 floats
  unsigned ua = __float_as_uint(a), ub = __float_as_uint(b);
  ua += 0x7fff + ((ua >> 16) & 1);
  ub += 0x7fff + ((ub >> 16) & 1);
  return (ua >> 16) | (ub & 0xffff0000u);
}
__device__ inline unsigned short bf16_1(float a) {
  unsigned u = __float_as_uint(a);
  u += 0x7fff + ((u >> 16) & 1);
  return (unsigned short)(u >> 16);
}
__device__ inline float bf_lo(unsigned u) { return __uint_as_float(u << 16); }
__device__ inline float bf_hi(unsigned u) { return __uint_as_float(u & 0xffff0000u); }
__device__ inline bf16x8 as_bf16x8(uint4 v) { bf16x8 r; __builtin_memcpy(&r, &v, 16); return r; }

// ---------- degree histogram ----------
__global__ void count_deg_k(const int* __restrict__ ei, int E, int* __restrict__ cnt) {
  int i = blockIdx.x * blockDim.x + threadIdx.x;
  int stride = gridDim.x * blockDim.x;
  for (; i < E; i += stride) {
    atomicAdd(&cnt[ei[E + i]], 1);
  }
}

__global__ void dinv_k(const int* __restrict__ cnt, float* __restrict__ dinv, int n) {
  int i = blockIdx.x * blockDim.x + threadIdx.x;
  if (i < n) dinv[i] = rsqrtf((float)cnt[i] + 1.0f);  // +1 self-loop
}

// ---------- hierarchical exclusive scan of cnt[0..n) -> off ----------
__global__ __launch_bounds__(256)
void scan1_k(const int* __restrict__ cnt, int n, int* __restrict__ bsum) {
  __shared__ int sd[256];
  int base = blockIdx.x * SCHUNK + threadIdx.x * 8;
  int s = 0;
#pragma unroll
  for (int j = 0; j < 8; ++j) {
    int i = base + j;
    if (i < n) s += cnt[i];
  }
  sd[threadIdx.x] = s;
  __syncthreads();
  for (int ofs = 128; ofs > 0; ofs >>= 1) {
    if (threadIdx.x < ofs) sd[threadIdx.x] += sd[threadIdx.x + ofs];
    __syncthreads();
  }
  if (threadIdx.x == 0) bsum[blockIdx.x] = sd[0];
}

__global__ __launch_bounds__(256)
void scan2_k(int* __restrict__ bsum, int B, int* __restrict__ off, int n) {
  __shared__ int sd[256];
  int v = (threadIdx.x < B) ? bsum[threadIdx.x] : 0;
  sd[threadIdx.x] = v;
  __syncthreads();
#pragma unroll
  for (int ofs = 1; ofs < 256; ofs <<= 1) {
    int t = (threadIdx.x >= ofs) ? sd[threadIdx.x - ofs] : 0;
    __syncthreads();
    sd[threadIdx.x] += t;
    __syncthreads();
  }
  if (threadIdx.x < B) bsum[threadIdx.x] = sd[threadIdx.x] - v;  // exclusive
  if (threadIdx.x == 255) off[n] = sd[255];                      // total == E
}

__global__ __launch_bounds__(256)
void scan3_k(const int* __restrict__ cnt, int n, const int* __restrict__ bsum,
             int* __restrict__ off) {
  __shared__ int sd[256];
  int base = blockIdx.x * SCHUNK + threadIdx.x * 8;
  int v[8];
  int s = 0;
#pragma unroll
  for (int j = 0; j < 8; ++j) {
    int i = base + j;
    v[j] = (i < n) ? cnt[i] : 0;
    s += v[j];
  }
  sd[threadIdx.x] = s;
  __syncthreads();
#pragma unroll
  for (int ofs = 1; ofs < 256; ofs <<= 1) {
    int t = (threadIdx.x >= ofs) ? sd[threadIdx.x - ofs] : 0;
    __syncthreads();
    sd[threadIdx.x] += t;
    __syncthreads();
  }
  int running = bsum[blockIdx.x] + sd[threadIdx.x] - s;  // exclusive prefix
#pragma unroll
  for (int j = 0; j < 8; ++j) {
    int i = base + j;
    if (i < n) off[i] = running;
    running += v[j];
  }
}

// ---------- contention-free counting sort of edges into buckets ----------
__global__ __launch_bounds__(256)
void hist_k(const int* __restrict__ ei, int E, int K, int* __restrict__ hist) {
  __shared__ int lh[1024];
  for (int i = threadIdx.x; i < K; i += 256) lh[i] = 0;
  __syncthreads();
  int C = (E + gridDim.x - 1) / gridDim.x;
  int beg = blockIdx.x * C;
  int end = min(E, beg + C);
  for (int i = beg + threadIdx.x; i < end; i += 256)
    atomicAdd(&lh[ei[E + i] >> BSHIFT], 1);
  __syncthreads();
  for (int i = threadIdx.x; i < K; i += 256) hist[blockIdx.x * K + i] = lh[i];
}

__global__ __launch_bounds__(G_SORT)
void hscan_k(int* __restrict__ hist, int K, const int* __restrict__ off) {
  __shared__ int sd[G_SORT];
  int k = blockIdx.x;
  int v = hist[threadIdx.x * K + k];
  sd[threadIdx.x] = v;
  __syncthreads();
#pragma unroll
  for (int ofs = 1; ofs < G_SORT; ofs <<= 1) {
    int t = (threadIdx.x >= ofs) ? sd[threadIdx.x - ofs] : 0;
    __syncthreads();
    sd[threadIdx.x] += t;
    __syncthreads();
  }
  hist[threadIdx.x * K + k] = off[k << BSHIFT] + sd[threadIdx.x] - v;  // exclusive + base
}

__global__ __launch_bounds__(256)
void fillc_k(const int* __restrict__ ei, int E, int K, const int* __restrict__ hist,
             unsigned* __restrict__ ent) {
  __shared__ int lcur[1024];
  for (int i = threadIdx.x; i < K; i += 256) lcur[i] = hist[blockIdx.x * K + i];
  __syncthreads();
  int C = (E + gridDim.x - 1) / gridDim.x;
  int beg = blockIdx.x * C;
  int end = min(E, beg + C);
  for (int i = beg + threadIdx.x; i < end; i += 256) {
    int s = ei[i];
    int d = ei[E + i];
    int pos = atomicAdd(&lcur[d >> BSHIFT], 1);
    ent[pos] = ((unsigned)(d & ((1 << BSHIFT) - 1)) << 25) | (unsigned)s;
  }
}

__global__ __launch_bounds__(256)
void fill2_k(const int* __restrict__ off, const unsigned* __restrict__ ent,
             int* __restrict__ ssrc, int n) {
  __shared__ int lbase[1 << BSHIFT];
  __shared__ int lcnt[1 << BSHIFT];
  int node0 = blockIdx.x << BSHIFT;
  int node1 = min(node0 + (1 << BSHIFT), n);
  int nn = node1 - node0;
  if (threadIdx.x < nn) {
    lbase[threadIdx.x] = off[node0 + threadIdx.x];
    lcnt[threadIdx.x] = 0;
  }
  __syncthreads();
  int beg = off[node0], end = off[node1];
  for (int i = beg + threadIdx.x; i < end; i += 256) {
    unsigned p = ent[i];
    int dl = (int)(p >> 25);
    int s  = (int)(p & ((1u << 25) - 1));
    int pos = lbase[dl] + atomicAdd(&lcnt[dl], 1);
    ssrc[pos] = s;
  }
}

// ---------- MFMA matmul: HSb[row][c] (bf16) = dinv[row] * (X @ W)[row][c] ----------
// X fp32 [n][128], W fp32 [128][OUT]. bf16 conversion of both operands in LDS.
// Fragment k-map trick: A and B loaded with the SAME (lane-group, elem)->k map,
// so the contraction is correct for any such map; only C/D layout (HW-verified,
// col=lane&15, row=(lane>>4)*4+reg) must be exact.
template<int OUT>
__global__ __launch_bounds__(256)
void mfma_matmul_k(const float* __restrict__ X, const float* __restrict__ W,
                   const float* __restrict__ dinv, unsigned short* __restrict__ HSb,
                   int n, int ntiles) {
  constexpr int KP = 136;  // padded K row stride in bf16 (272B = 17*16B): spreads b128 frag reads
  __shared__ unsigned short Wt[OUT * KP];  // W transposed: Wt[c][k]
  __shared__ unsigned short Xb[64 * KP];   // X tile: 64 rows x 128 k

  const int tid = threadIdx.x;
  // stage W (transposed, bf16) once per block
  for (int i = tid; i < 128 * OUT; i += 256) {
    int k = i / OUT, c = i % OUT;
    Wt[c * KP + k] = bf16_1(W[i]);
  }
  const int wv  = tid >> 6;   // wave 0..3 -> rows [wv*16, wv*16+16)
  const int l   = tid & 63;
  const int l16 = l & 15, lg = l >> 4;

  for (int t = blockIdx.x; t < ntiles; t += gridDim.x) {
    int row0 = t * 64;
    __syncthreads();  // previous tile's readers done (also orders first Wt staging)
    // stage X tile (fp32 -> bf16), 8 cols per unit, coalesced global reads
    for (int i = tid; i < 64 * 16; i += 256) {
      int r = i >> 4, kg8 = i & 15;
      int grow = row0 + r;
      uint4 p = make_uint4(0, 0, 0, 0);
      if (grow < n) {
        const float* xp = &X[(long long)grow * 128 + kg8 * 8];
        float4 a = *(const float4*)xp;
        float4 b = *(const float4*)(xp + 4);
        p.x = pk_bf16(a.x, a.y); p.y = pk_bf16(a.z, a.w);
        p.z = pk_bf16(b.x, b.y); p.w = pk_bf16(b.z, b.w);
      }
      *(uint4*)&Xb[r * KP + kg8 * 8] = p;
    }
    __syncthreads();

    f32x4 acc[OUT / 16];
#pragma unroll
    for (int nt = 0; nt < OUT / 16; ++nt) acc[nt] = (f32x4){0.f, 0.f, 0.f, 0.f};
#pragma unroll
    for (int kc = 0; kc < 4; ++kc) {
      uint4 av = *(const uint4*)&Xb[(wv * 16 + l16) * KP + kc * 32 + lg * 8];
      bf16x8 a = as_bf16x8(av);
#pragma unroll
      for (int nt = 0; nt < OUT / 16; ++nt) {
        uint4 bv = *(const uint4*)&Wt[(nt * 16 + l16) * KP + kc * 32 + lg * 8];
        acc[nt] = __builtin_amdgcn_mfma_f32_16x16x32_bf16(a, as_bf16x8(bv), acc[nt], 0, 0, 0);
      }
    }
    // epilogue: D row = (lane>>4)*4 + reg, col = nt*16 + (lane&15)  [HW-verified]
    int rbase = row0 + wv * 16 + lg * 4;
#pragma unroll
    for (int reg = 0; reg < 4; ++reg) {
      int grow = rbase + reg;
      if (grow < n) {
        float di = dinv[grow];
#pragma unroll
        for (int nt = 0; nt < OUT / 16; ++nt)
          HSb[(long long)grow * OUT + nt * 16 + l16] = bf16_1(acc[nt][reg] * di);
      }
    }
  }
}

// ---------- CSR aggregate (bf16 gathers, fp32 accumulate) + fused finalize ----------
template<int OUT>
__global__ __launch_bounds__(256)
void aggregate_k(const int* __restrict__ off, const int* __restrict__ ssrc,
                 const uint4* __restrict__ HSv, const float* __restrict__ dinv,
                 const float* __restrict__ bias, float* __restrict__ Y, int n) {
  constexpr int TPR = OUT / 8;       // lanes per row: 16 (OUT=128) / 8 (OUT=64); 16B per lane
  constexpr int RPB = 256 / TPR;     // rows per block
  const int lane = threadIdx.x % TPR;
  const int r    = threadIdx.x / TPR;
  const int c8   = lane * 8;
  const float4 bb0 = *(const float4*)&bias[c8];
  const float4 bb1 = *(const float4*)&bias[c8 + 4];

  for (int d = blockIdx.x * RPB + r; d < n; d += gridDim.x * RPB) {
    int beg = off[d], end = off[d + 1];
    float acc[8];
    {
      uint4 g = HSv[(long long)d * TPR + lane];  // self-loop term
      acc[0] = bf_lo(g.x); acc[1] = bf_hi(g.x);
      acc[2] = bf_lo(g.y); acc[3] = bf_hi(g.y);
      acc[4] = bf_lo(g.z); acc[5] = bf_hi(g.z);
      acc[6] = bf_lo(g.w); acc[7] = bf_hi(g.w);
    }
    int e = beg;
    for (; e + 4 <= end; e += 4) {  // 4 independent gathers in flight
      int s0 = ssrc[e], s1 = ssrc[e + 1], s2 = ssrc[e + 2], s3 = ssrc[e + 3];
      uint4 g0 = HSv[(long long)s0 * TPR + lane];
      uint4 g1 = HSv[(long long)s1 * TPR + lane];
      uint4 g2 = HSv[(long long)s2 * TPR + lane];
      uint4 g3 = HSv[(long long)s3 * TPR + lane];
      acc[0] += (bf_lo(g0.x) + bf_lo(g1.x)) + (bf_lo(g2.x) + bf_lo(g3.x));
      acc[1] += (bf_hi(g0.x) + bf_hi(g1.x)) + (bf_hi(g2.x) + bf_hi(g3.x));
      acc[2] += (bf_lo(g0.y) + bf_lo(g1.y)) + (bf_lo(g2.y) + bf_lo(g3.y));
      acc[3] += (bf_hi(g0.y) + bf_hi(g1.y)) + (bf_hi(g2.y) + bf_hi(g3.y));
      acc[4] += (bf_lo(g0.z) + bf_lo(g1.z)) + (bf_lo(g2.z) + bf_lo(g3.z));
      acc[5] += (bf_hi(g0.z) + bf_hi(g1.z)) + (bf_hi(g2.z) + bf_hi(g3.z));
      acc[6] += (bf_lo(g0.w) + bf_lo(g1.w)) + (bf_lo(g2.w) + bf_lo(g3.w));
      acc[7] += (bf_hi(g0.w) + bf_hi(g1.w)) + (bf_hi(g2.w) + bf_hi(g3.w));
    }
    for (; e < end; ++e) {
      uint4 g = HSv[(long long)ssrc[e] * TPR + lane];
      acc[0] += bf_lo(g.x); acc[1] += bf_hi(g.x);
      acc[2] += bf_lo(g.y); acc[3] += bf_hi(g.y);
      acc[4] += bf_lo(g.z); acc[5] += bf_hi(g.z);
      acc[6] += bf_lo(g.w); acc[7] += bf_hi(g.w);
    }
    float di = dinv[d];
    float4 y0, y1;
    y0.x = fmaxf(fmaf(di, acc[0], bb0.x), 0.f);
    y0.y = fmaxf(fmaf(di, acc[1], bb0.y), 0.f);
    y0.z = fmaxf(fmaf(di, acc[2], bb0.z), 0.f);
    y0.w = fmaxf(fmaf(di, acc[3], bb0.w), 0.f);
    y1.x = fmaxf(fmaf(di, acc[4], bb1.x), 0.f);
    y1.y = fmaxf(fmaf(di, acc[5], bb1.y), 0.f);
    y1.z = fmaxf(fmaf(di, acc[6], bb1.z), 0.f);
    y1.w = fmaxf(fmaf(di, acc[7], bb1.w), 0.f);
    *(float4*)&Y[(long long)d * OUT + c8] = y0;
    *(float4*)&Y[(long long)d * OUT + c8 + 4] = y1;
  }
}

extern "C" void kernel_launch(void* const* d_in, const int* in_sizes, int n_in,
                              void* d_out, int out_size, void* d_ws, size_t ws_size,
                              hipStream_t stream) {
  const float* x  = (const float*)d_in[0];
  const int*   ei = (const int*)d_in[1];
  const float* W1 = (const float*)d_in[2];
  const float* b1 = (const float*)d_in[3];
  const float* W2 = (const float*)d_in[4];
  const float* b2 = (const float*)d_in[5];
  float* out = (float*)d_out;

  const int n = in_sizes[0] / IN_DIM;   // 100000
  const int E = in_sizes[1] / 2;        // 1600000

  // workspace layout (bytes)
  char* ws = (char*)d_ws;
  size_t o = 0;
  auto alloc = [&](size_t bytes) { char* p = ws + o; o = (o + bytes + 255) & ~(size_t)255; return p; };
  float* dinv   = (float*)alloc((size_t)n * 4);
  int*   off    = (int*)  alloc((size_t)(n + 1) * 4);
  int*   cnt    = (int*)  alloc((size_t)n * 4);
  int*   bsum   = (int*)  alloc((size_t)256 * 4);
  int*   hist   = (int*)  alloc((size_t)G_SORT * 1024 * 4);  // 1 MB
  int*   ssrc   = (int*)  alloc((size_t)E * 4);
  unsigned short* A = (unsigned short*)alloc((size_t)n * 128 * 2);  // bf16 HS1, then bf16 HS2
  float* B      = (float*)alloc((size_t)n * 128 * 4);               // fp32 x1 (layer-1 output)
  // ent (6.4 MB) overlays B: only live during CSR build, before B is written
  unsigned* ent = (unsigned*)B;

  const int nb = (n + 255) / 256;
  const int nscan = (n + SCHUNK - 1) / SCHUNK;      // 49 blocks (<= 256 required)
  const int NB = (n + (1 << BSHIFT) - 1) >> BSHIFT; // 782 buckets (<= 1024 required)
  const int ntiles = (n + 63) / 64;                 // 1563 row-tiles of 64

  // ----- CSR build (once, reused by both layers) -----
  hipMemsetAsync(cnt, 0, (size_t)n * 4, stream);
  count_deg_k<<<2048, 256, 0, stream>>>(ei, E, cnt);
  dinv_k<<<nb, 256, 0, stream>>>(cnt, dinv, n);
  scan1_k<<<nscan, 256, 0, stream>>>(cnt, n, bsum);
  scan2_k<<<1, 256, 0, stream>>>(bsum, nscan, off, n);
  scan3_k<<<nscan, 256, 0, stream>>>(cnt, n, bsum, off);
  hist_k<<<G_SORT, 256, 0, stream>>>(ei, E, NB, hist);
  hscan_k<<<NB, G_SORT, 0, stream>>>(hist, NB, off);
  fillc_k<<<G_SORT, 256, 0, stream>>>(ei, E, NB, hist, ent);
  fill2_k<<<NB, 256, 0, stream>>>(off, ent, ssrc, n);

  // ----- layer 1 (128 -> 128) -----
  mfma_matmul_k<128><<<782, 256, 0, stream>>>(x, W1, dinv, A, n, ntiles);
  aggregate_k<128><<<4096, 256, 0, stream>>>(off, ssrc, (const uint4*)A, dinv, b1, B, n);

  // ----- layer 2 (128 -> 64) -----
  mfma_matmul_k<64><<<782, 256, 0, stream>>>(B, W2, dinv, A, n, ntiles);
  aggregate_k<64><<<4096, 256, 0, stream>>>(off, ssrc, (const uint4*)A, dinv, b2, out, n);
}

// Round 9
// 188.879 us; speedup vs baseline: 4.5205x; 1.4094x over previous
//
#include <hip/hip_runtime.h>

constexpr int IN_DIM = 128;
constexpr int BSHIFT = 7;     // 128 nodes per bucket
constexpr int G_SORT = 256;   // blocks in the counting-sort passes
// NOTE: requires n <= 2^25 (src packs in 25 bits), n <= 1024<<BSHIFT (LDS hist),
// and NB <= 1024 (single-block bucket scan); n=100000 ok.

typedef float  f32x4  __attribute__((ext_vector_type(4)));
typedef short  bf16x8 __attribute__((ext_vector_type(8)));

// bf16 helpers: storage-only compression (accumulate in fp32)
__device__ inline unsigned pk_bf16(float a, float b) {  // RTNE pack of 2 floats
  unsigned ua = __float_as_uint(a), ub = __float_as_uint(b);
  ua += 0x7fff + ((ua >> 16) & 1);
  ub += 0x7fff + ((ub >> 16) & 1);
  return (ua >> 16) | (ub & 0xffff0000u);
}
__device__ inline unsigned short bf16_1(float a) {
  unsigned u = __float_as_uint(a);
  u += 0x7fff + ((u >> 16) & 1);
  return (unsigned short)(u >> 16);
}
__device__ inline float bf_lo(unsigned u) { return __uint_as_float(u << 16); }
__device__ inline float bf_hi(unsigned u) { return __uint_as_float(u & 0xffff0000u); }
__device__ inline bf16x8 as_bf16x8(uint4 v) { bf16x8 r; __builtin_memcpy(&r, &v, 16); return r; }

// ---------- pass A: per-block LDS bucket histograms (no global atomics) ----------
__global__ __launch_bounds__(256)
void hist_k(const int* __restrict__ ei, int E, int K, int* __restrict__ hist) {
  __shared__ int lh[1024];
  for (int i = threadIdx.x; i < K; i += 256) lh[i] = 0;
  __syncthreads();
  int C = (E + gridDim.x - 1) / gridDim.x;
  int beg = blockIdx.x * C;
  int end = min(E, beg + C);
  for (int i = beg + threadIdx.x; i < end; i += 256)
    atomicAdd(&lh[ei[E + i] >> BSHIFT], 1);
  __syncthreads();
  for (int i = threadIdx.x; i < K; i += 256) hist[blockIdx.x * K + i] = lh[i];
}

// ---------- pass B: column-scan hist over blocks; emit bucket totals ----------
// one block per bucket; blockDim == G_SORT; hist[g][k] -> exclusive offset within bucket
__global__ __launch_bounds__(G_SORT)
void hsum_k(int* __restrict__ hist, int K, int* __restrict__ btot) {
  __shared__ int sd[G_SORT];
  int k = blockIdx.x;
  int v = hist[threadIdx.x * K + k];
  sd[threadIdx.x] = v;
  __syncthreads();
#pragma unroll
  for (int ofs = 1; ofs < G_SORT; ofs <<= 1) {
    int t = (threadIdx.x >= ofs) ? sd[threadIdx.x - ofs] : 0;
    __syncthreads();
    sd[threadIdx.x] += t;
    __syncthreads();
  }
  hist[threadIdx.x * K + k] = sd[threadIdx.x] - v;       // exclusive within bucket
  if (threadIdx.x == G_SORT - 1) btot[k] = sd[threadIdx.x];  // bucket total
}

// ---------- pass C: single-block exclusive scan of bucket totals -> bkbase ----------
__global__ __launch_bounds__(1024)
void bscan_k(const int* __restrict__ btot, int NB, int* __restrict__ bkbase,
             int* __restrict__ off, int n, int E) {
  __shared__ int sd[1024];
  int v = (threadIdx.x < NB) ? btot[threadIdx.x] : 0;
  sd[threadIdx.x] = v;
  __syncthreads();
#pragma unroll
  for (int ofs = 1; ofs < 1024; ofs <<= 1) {
    int t = (threadIdx.x >= ofs) ? sd[threadIdx.x - ofs] : 0;
    __syncthreads();
    sd[threadIdx.x] += t;
    __syncthreads();
  }
  if (threadIdx.x < NB) bkbase[threadIdx.x] = sd[threadIdx.x] - v;  // exclusive
  if (threadIdx.x == 0) { bkbase[NB] = E; off[n] = E; }
}

// ---------- pass D: place packed (d_local,src) at reserved positions ----------
__global__ __launch_bounds__(256)
void fillc_k(const int* __restrict__ ei, int E, int K, const int* __restrict__ hist,
             const int* __restrict__ bkbase, unsigned* __restrict__ ent) {
  __shared__ int lcur[1024];
  for (int i = threadIdx.x; i < K; i += 256)
    lcur[i] = bkbase[i] + hist[blockIdx.x * K + i];
  __syncthreads();
  int C = (E + gridDim.x - 1) / gridDim.x;
  int beg = blockIdx.x * C;
  int end = min(E, beg + C);
  for (int i = beg + threadIdx.x; i < end; i += 256) {
    int s = ei[i];
    int d = ei[E + i];
    int pos = atomicAdd(&lcur[d >> BSHIFT], 1);
    ent[pos] = ((unsigned)(d & ((1 << BSHIFT) - 1)) << 25) | (unsigned)s;
  }
}

// ---------- pass E: per-bucket -> node-exact CSR; derive cnt/off/dinv as by-products ----------
__global__ __launch_bounds__(256)
void fill2_k(const int* __restrict__ bkbase, const unsigned* __restrict__ ent,
             int* __restrict__ ssrc, int* __restrict__ off, float* __restrict__ dinv,
             int n) {
  constexpr int BK = 1 << BSHIFT;  // 128
  __shared__ int lcnt[BK];
  __shared__ int lbase[BK];
  __shared__ int sd[BK];
  const int tid = threadIdx.x;
  int node0 = blockIdx.x << BSHIFT;
  int nn = min(BK, n - node0);
  int beg = bkbase[blockIdx.x], end = bkbase[blockIdx.x + 1];

  if (tid < BK) lcnt[tid] = 0;
  __syncthreads();
  // pre-pass: per-node counts within this bucket (LDS atomics, L2-resident ent)
  for (int i = beg + tid; i < end; i += 256)
    atomicAdd(&lcnt[ent[i] >> 25], 1);
  __syncthreads();
  int v = (tid < BK) ? lcnt[tid] : 0;
  if (tid < BK) sd[tid] = v;
  __syncthreads();
#pragma unroll
  for (int ofs = 1; ofs < BK; ofs <<= 1) {
    int t = 0;
    if (tid < BK && tid >= ofs) t = sd[tid - ofs];
    __syncthreads();
    if (tid < BK) sd[tid] += t;
    __syncthreads();
  }
  if (tid < BK) {
    int base = beg + sd[tid] - v;  // node-exclusive offset + bucket base
    lbase[tid] = base;
    lcnt[tid] = 0;
    if (tid < nn) {
      off[node0 + tid] = base;
      dinv[node0 + tid] = rsqrtf((float)v + 1.0f);  // +1 self-loop
    }
  }
  __syncthreads();
  // placement pass
  for (int i = beg + tid; i < end; i += 256) {
    unsigned p = ent[i];
    int dl = (int)(p >> 25);
    int s  = (int)(p & ((1u << 25) - 1));
    int pos = lbase[dl] + atomicAdd(&lcnt[dl], 1);
    ssrc[pos] = s;
  }
}

// ---------- MFMA matmul: HSb[row][c] (bf16) = dinv[row] * (X @ W)[row][c] ----------
template<int OUT>
__global__ __launch_bounds__(256)
void mfma_matmul_k(const float* __restrict__ X, const float* __restrict__ W,
                   const float* __restrict__ dinv, unsigned short* __restrict__ HSb,
                   int n, int ntiles) {
  constexpr int KP = 136;  // padded K row stride in bf16 (272B): spreads b128 frag reads
  __shared__ unsigned short Wt[OUT * KP];  // W transposed: Wt[c][k]
  __shared__ unsigned short Xb[64 * KP];   // X tile: 64 rows x 128 k

  const int tid = threadIdx.x;
  for (int i = tid; i < 128 * OUT; i += 256) {
    int k = i / OUT, c = i % OUT;
    Wt[c * KP + k] = bf16_1(W[i]);
  }
  const int wv  = tid >> 6;
  const int l   = tid & 63;
  const int l16 = l & 15, lg = l >> 4;

  for (int t = blockIdx.x; t < ntiles; t += gridDim.x) {
    int row0 = t * 64;
    __syncthreads();
    for (int i = tid; i < 64 * 16; i += 256) {
      int r = i >> 4, kg8 = i & 15;
      int grow = row0 + r;
      uint4 p = make_uint4(0, 0, 0, 0);
      if (grow < n) {
        const float* xp = &X[(long long)grow * 128 + kg8 * 8];
        float4 a = *(const float4*)xp;
        float4 b = *(const float4*)(xp + 4);
        p.x = pk_bf16(a.x, a.y); p.y = pk_bf16(a.z, a.w);
        p.z = pk_bf16(b.x, b.y); p.w = pk_bf16(b.z, b.w);
      }
      *(uint4*)&Xb[r * KP + kg8 * 8] = p;
    }
    __syncthreads();

    f32x4 acc[OUT / 16];
#pragma unroll
    for (int nt = 0; nt < OUT / 16; ++nt) acc[nt] = (f32x4){0.f, 0.f, 0.f, 0.f};
#pragma unroll
    for (int kc = 0; kc < 4; ++kc) {
      uint4 av = *(const uint4*)&Xb[(wv * 16 + l16) * KP + kc * 32 + lg * 8];
      bf16x8 a = as_bf16x8(av);
#pragma unroll
      for (int nt = 0; nt < OUT / 16; ++nt) {
        uint4 bv = *(const uint4*)&Wt[(nt * 16 + l16) * KP + kc * 32 + lg * 8];
        acc[nt] = __builtin_amdgcn_mfma_f32_16x16x32_bf16(a, as_bf16x8(bv), acc[nt], 0, 0, 0);
      }
    }
    int rbase = row0 + wv * 16 + lg * 4;
#pragma unroll
    for (int reg = 0; reg < 4; ++reg) {
      int grow = rbase + reg;
      if (grow < n) {
        float di = dinv[grow];
#pragma unroll
        for (int nt = 0; nt < OUT / 16; ++nt)
          HSb[(long long)grow * OUT + nt * 16 + l16] = bf16_1(acc[nt][reg] * di);
      }
    }
  }
}

// ---------- CSR aggregate (bf16 gathers, fp32 accumulate) + fused finalize ----------
template<int OUT>
__global__ __launch_bounds__(256)
void aggregate_k(const int* __restrict__ off, const int* __restrict__ ssrc,
                 const uint4* __restrict__ HSv, const float* __restrict__ dinv,
                 const float* __restrict__ bias, float* __restrict__ Y, int n) {
  constexpr int TPR = OUT / 8;       // lanes per row: 16 (OUT=128) / 8 (OUT=64)
  constexpr int RPB = 256 / TPR;     // rows per block
  const int lane = threadIdx.x % TPR;
  const int r    = threadIdx.x / TPR;
  const int c8   = lane * 8;
  const float4 bb0 = *(const float4*)&bias[c8];
  const float4 bb1 = *(const float4*)&bias[c8 + 4];

  for (int d = blockIdx.x * RPB + r; d < n; d += gridDim.x * RPB) {
    int beg = off[d], end = off[d + 1];
    float acc[8];
    {
      uint4 g = HSv[(long long)d * TPR + lane];  // self-loop term
      acc[0] = bf_lo(g.x); acc[1] = bf_hi(g.x);
      acc[2] = bf_lo(g.y); acc[3] = bf_hi(g.y);
      acc[4] = bf_lo(g.z); acc[5] = bf_hi(g.z);
      acc[6] = bf_lo(g.w); acc[7] = bf_hi(g.w);
    }
    int e = beg;
    for (; e + 4 <= end; e += 4) {  // 4 independent gathers in flight
      int s0 = ssrc[e], s1 = ssrc[e + 1], s2 = ssrc[e + 2], s3 = ssrc[e + 3];
      uint4 g0 = HSv[(long long)s0 * TPR + lane];
      uint4 g1 = HSv[(long long)s1 * TPR + lane];
      uint4 g2 = HSv[(long long)s2 * TPR + lane];
      uint4 g3 = HSv[(long long)s3 * TPR + lane];
      acc[0] += (bf_lo(g0.x) + bf_lo(g1.x)) + (bf_lo(g2.x) + bf_lo(g3.x));
      acc[1] += (bf_hi(g0.x) + bf_hi(g1.x)) + (bf_hi(g2.x) + bf_hi(g3.x));
      acc[2] += (bf_lo(g0.y) + bf_lo(g1.y)) + (bf_lo(g2.y) + bf_lo(g3.y));
      acc[3] += (bf_hi(g0.y) + bf_hi(g1.y)) + (bf_hi(g2.y) + bf_hi(g3.y));
      acc[4] += (bf_lo(g0.z) + bf_lo(g1.z)) + (bf_lo(g2.z) + bf_lo(g3.z));
      acc[5] += (bf_hi(g0.z) + bf_hi(g1.z)) + (bf_hi(g2.z) + bf_hi(g3.z));
      acc[6] += (bf_lo(g0.w) + bf_lo(g1.w)) + (bf_lo(g2.w) + bf_lo(g3.w));
      acc[7] += (bf_hi(g0.w) + bf_hi(g1.w)) + (bf_hi(g2.w) + bf_hi(g3.w));
    }
    for (; e < end; ++e) {
      uint4 g = HSv[(long long)ssrc[e] * TPR + lane];
      acc[0] += bf_lo(g.x); acc[1] += bf_hi(g.x);
      acc[2] += bf_lo(g.y); acc[3] += bf_hi(g.y);
      acc[4] += bf_lo(g.z); acc[5] += bf_hi(g.z);
      acc[6] += bf_lo(g.w); acc[7] += bf_hi(g.w);
    }
    float di = dinv[d];
    float4 y0, y1;
    y0.x = fmaxf(fmaf(di, acc[0], bb0.x), 0.f);
    y0.y = fmaxf(fmaf(di, acc[1], bb0.y), 0.f);
    y0.z = fmaxf(fmaf(di, acc[2], bb0.z), 0.f);
    y0.w = fmaxf(fmaf(di, acc[3], bb0.w), 0.f);
    y1.x = fmaxf(fmaf(di, acc[4], bb1.x), 0.f);
    y1.y = fmaxf(fmaf(di, acc[5], bb1.y), 0.f);
    y1.z = fmaxf(fmaf(di, acc[6], bb1.z), 0.f);
    y1.w = fmaxf(fmaf(di, acc[7], bb1.w), 0.f);
    *(float4*)&Y[(long long)d * OUT + c8] = y0;
    *(float4*)&Y[(long long)d * OUT + c8 + 4] = y1;
  }
}

extern "C" void kernel_launch(void* const* d_in, const int* in_sizes, int n_in,
                              void* d_out, int out_size, void* d_ws, size_t ws_size,
                              hipStream_t stream) {
  const float* x  = (const float*)d_in[0];
  const int*   ei = (const int*)d_in[1];
  const float* W1 = (const float*)d_in[2];
  const float* b1 = (const float*)d_in[3];
  const float* W2 = (const float*)d_in[4];
  const float* b2 = (const float*)d_in[5];
  float* out = (float*)d_out;

  const int n = in_sizes[0] / IN_DIM;   // 100000
  const int E = in_sizes[1] / 2;        // 1600000

  // workspace layout (bytes)
  char* ws = (char*)d_ws;
  size_t o = 0;
  auto alloc = [&](size_t bytes) { char* p = ws + o; o = (o + bytes + 255) & ~(size_t)255; return p; };
  float* dinv   = (float*)alloc((size_t)n * 4);
  int*   off    = (int*)  alloc((size_t)(n + 1) * 4);
  int*   btot   = (int*)  alloc((size_t)1024 * 4);
  int*   bkbase = (int*)  alloc((size_t)1025 * 4);
  int*   hist   = (int*)  alloc((size_t)G_SORT * 1024 * 4);  // 1 MB
  int*   ssrc   = (int*)  alloc((size_t)E * 4);
  unsigned short* A = (unsigned short*)alloc((size_t)n * 128 * 2);  // bf16 HS1, then bf16 HS2
  float* B      = (float*)alloc((size_t)n * 128 * 4);               // fp32 x1 (layer-1 output)
  // ent (6.4 MB) overlays B: only live during CSR build, before B is written
  unsigned* ent = (unsigned*)B;

  const int NB = (n + (1 << BSHIFT) - 1) >> BSHIFT; // 782 buckets (<= 1024 required)
  const int ntiles = (n + 63) / 64;                 // 1563 row-tiles of 64

  // ----- CSR build (zero global atomics; cnt/off/dinv derived in-sort) -----
  hist_k<<<G_SORT, 256, 0, stream>>>(ei, E, NB, hist);
  hsum_k<<<NB, G_SORT, 0, stream>>>(hist, NB, btot);
  bscan_k<<<1, 1024, 0, stream>>>(btot, NB, bkbase, off, n, E);
  fillc_k<<<G_SORT, 256, 0, stream>>>(ei, E, NB, hist, bkbase, ent);
  fill2_k<<<NB, 256, 0, stream>>>(bkbase, ent, ssrc, off, dinv, n);

  // ----- layer 1 (128 -> 128) -----
  mfma_matmul_k<128><<<782, 256, 0, stream>>>(x, W1, dinv, A, n, ntiles);
  aggregate_k<128><<<4096, 256, 0, stream>>>(off, ssrc, (const uint4*)A, dinv, b1, B, n);

  // ----- layer 2 (128 -> 64) -----
  mfma_matmul_k<64><<<782, 256, 0, stream>>>(B, W2, dinv, A, n, ntiles);
  aggregate_k<64><<<4096, 256, 0, stream>>>(off, ssrc, (const uint4*)A, dinv, b2, out, n);
}

// Round 10
// 186.206 us; speedup vs baseline: 4.5853x; 1.0143x over previous
//
#include <hip/hip_runtime.h>

constexpr int IN_DIM = 128;
constexpr int BSHIFT = 7;     // 128 nodes per bucket
constexpr int G_SORT = 256;   // blocks in the counting-sort passes
// NOTE: requires n <= 2^25 (src packs in 25 bits), n <= 1024<<BSHIFT (LDS hist),
// and NB <= 1024 (single-block bucket scan); n=100000 ok.

typedef float  f32x4  __attribute__((ext_vector_type(4)));
typedef short  bf16x8 __attribute__((ext_vector_type(8)));

// bf16 helpers: storage-only compression (accumulate in fp32)
__device__ inline unsigned pk_bf16(float a, float b) {  // RTNE pack of 2 floats
  unsigned ua = __float_as_uint(a), ub = __float_as_uint(b);
  ua += 0x7fff + ((ua >> 16) & 1);
  ub += 0x7fff + ((ub >> 16) & 1);
  return (ua >> 16) | (ub & 0xffff0000u);
}
__device__ inline unsigned short bf16_1(float a) {
  unsigned u = __float_as_uint(a);
  u += 0x7fff + ((u >> 16) & 1);
  return (unsigned short)(u >> 16);
}
__device__ inline float bf_lo(unsigned u) { return __uint_as_float(u << 16); }
__device__ inline float bf_hi(unsigned u) { return __uint_as_float(u & 0xffff0000u); }
__device__ inline bf16x8 as_bf16x8(uint4 v) { bf16x8 r; __builtin_memcpy(&r, &v, 16); return r; }

// ---------- pass A: per-block LDS bucket histograms (no global atomics) ----------
__global__ __launch_bounds__(256)
void hist_k(const int* __restrict__ ei, int E, int K, int* __restrict__ hist) {
  __shared__ int lh[1024];
  for (int i = threadIdx.x; i < K; i += 256) lh[i] = 0;
  __syncthreads();
  int C = (E + gridDim.x - 1) / gridDim.x;
  int beg = blockIdx.x * C;
  int end = min(E, beg + C);
  for (int i = beg + threadIdx.x; i < end; i += 256)
    atomicAdd(&lh[ei[E + i] >> BSHIFT], 1);
  __syncthreads();
  for (int i = threadIdx.x; i < K; i += 256) hist[blockIdx.x * K + i] = lh[i];
}

// ---------- pass B: column-scan hist over blocks; emit bucket totals ----------
__global__ __launch_bounds__(G_SORT)
void hsum_k(int* __restrict__ hist, int K, int* __restrict__ btot) {
  __shared__ int sd[G_SORT];
  int k = blockIdx.x;
  int v = hist[threadIdx.x * K + k];
  sd[threadIdx.x] = v;
  __syncthreads();
#pragma unroll
  for (int ofs = 1; ofs < G_SORT; ofs <<= 1) {
    int t = (threadIdx.x >= ofs) ? sd[threadIdx.x - ofs] : 0;
    __syncthreads();
    sd[threadIdx.x] += t;
    __syncthreads();
  }
  hist[threadIdx.x * K + k] = sd[threadIdx.x] - v;       // exclusive within bucket
  if (threadIdx.x == G_SORT - 1) btot[k] = sd[threadIdx.x];  // bucket total
}

// ---------- pass C: single-block exclusive scan of bucket totals -> bkbase ----------
__global__ __launch_bounds__(1024)
void bscan_k(const int* __restrict__ btot, int NB, int* __restrict__ bkbase,
             int* __restrict__ off, int n, int E) {
  __shared__ int sd[1024];
  int v = (threadIdx.x < NB) ? btot[threadIdx.x] : 0;
  sd[threadIdx.x] = v;
  __syncthreads();
#pragma unroll
  for (int ofs = 1; ofs < 1024; ofs <<= 1) {
    int t = (threadIdx.x >= ofs) ? sd[threadIdx.x - ofs] : 0;
    __syncthreads();
    sd[threadIdx.x] += t;
    __syncthreads();
  }
  if (threadIdx.x < NB) bkbase[threadIdx.x] = sd[threadIdx.x] - v;  // exclusive
  if (threadIdx.x == 0) { bkbase[NB] = E; off[n] = E; }
}

// ---------- pass D: place packed (d_local,src) at reserved positions ----------
__global__ __launch_bounds__(256)
void fillc_k(const int* __restrict__ ei, int E, int K, const int* __restrict__ hist,
             const int* __restrict__ bkbase, unsigned* __restrict__ ent) {
  __shared__ int lcur[1024];
  for (int i = threadIdx.x; i < K; i += 256)
    lcur[i] = bkbase[i] + hist[blockIdx.x * K + i];
  __syncthreads();
  int C = (E + gridDim.x - 1) / gridDim.x;
  int beg = blockIdx.x * C;
  int end = min(E, beg + C);
  for (int i = beg + threadIdx.x; i < end; i += 256) {
    int s = ei[i];
    int d = ei[E + i];
    int pos = atomicAdd(&lcur[d >> BSHIFT], 1);
    ent[pos] = ((unsigned)(d & ((1 << BSHIFT) - 1)) << 25) | (unsigned)s;
  }
}

// ---------- pass E: per-bucket -> node-exact CSR; derive off/dinv as by-products ----------
__global__ __launch_bounds__(256)
void fill2_k(const int* __restrict__ bkbase, const unsigned* __restrict__ ent,
             int* __restrict__ ssrc, int* __restrict__ off, float* __restrict__ dinv,
             int n) {
  constexpr int BK = 1 << BSHIFT;  // 128
  __shared__ int lcnt[BK];
  __shared__ int lbase[BK];
  __shared__ int sd[BK];
  const int tid = threadIdx.x;
  int node0 = blockIdx.x << BSHIFT;
  int nn = min(BK, n - node0);
  int beg = bkbase[blockIdx.x], end = bkbase[blockIdx.x + 1];

  if (tid < BK) lcnt[tid] = 0;
  __syncthreads();
  for (int i = beg + tid; i < end; i += 256)
    atomicAdd(&lcnt[ent[i] >> 25], 1);
  __syncthreads();
  int v = (tid < BK) ? lcnt[tid] : 0;
  if (tid < BK) sd[tid] = v;
  __syncthreads();
#pragma unroll
  for (int ofs = 1; ofs < BK; ofs <<= 1) {
    int t = 0;
    if (tid < BK && tid >= ofs) t = sd[tid - ofs];
    __syncthreads();
    if (tid < BK) sd[tid] += t;
    __syncthreads();
  }
  if (tid < BK) {
    int base = beg + sd[tid] - v;
    lbase[tid] = base;
    lcnt[tid] = 0;
    if (tid < nn) {
      off[node0 + tid] = base;
      dinv[node0 + tid] = rsqrtf((float)v + 1.0f);  // +1 self-loop
    }
  }
  __syncthreads();
  for (int i = beg + tid; i < end; i += 256) {
    unsigned p = ent[i];
    int dl = (int)(p >> 25);
    int s  = (int)(p & ((1u << 25) - 1));
    int pos = lbase[dl] + atomicAdd(&lcnt[dl], 1);
    ssrc[pos] = s;
  }
}

// ---------- MFMA matmul: HSb[row][c] (bf16) = dinv[row] * (X @ W)[row][c] ----------
template<int OUT>
__global__ __launch_bounds__(256)
void mfma_matmul_k(const float* __restrict__ X, const float* __restrict__ W,
                   const float* __restrict__ dinv, unsigned short* __restrict__ HSb,
                   int n, int ntiles) {
  constexpr int KP = 136;  // padded K row stride in bf16 (272B)
  __shared__ unsigned short Wt[OUT * KP];
  __shared__ unsigned short Xb[64 * KP];

  const int tid = threadIdx.x;
  for (int i = tid; i < 128 * OUT; i += 256) {
    int k = i / OUT, c = i % OUT;
    Wt[c * KP + k] = bf16_1(W[i]);
  }
  const int wv  = tid >> 6;
  const int l   = tid & 63;
  const int l16 = l & 15, lg = l >> 4;

  for (int t = blockIdx.x; t < ntiles; t += gridDim.x) {
    int row0 = t * 64;
    __syncthreads();
    for (int i = tid; i < 64 * 16; i += 256) {
      int r = i >> 4, kg8 = i & 15;
      int grow = row0 + r;
      uint4 p = make_uint4(0, 0, 0, 0);
      if (grow < n) {
        const float* xp = &X[(long long)grow * 128 + kg8 * 8];
        float4 a = *(const float4*)xp;
        float4 b = *(const float4*)(xp + 4);
        p.x = pk_bf16(a.x, a.y); p.y = pk_bf16(a.z, a.w);
        p.z = pk_bf16(b.x, b.y); p.w = pk_bf16(b.z, b.w);
      }
      *(uint4*)&Xb[r * KP + kg8 * 8] = p;
    }
    __syncthreads();

    f32x4 acc[OUT / 16];
#pragma unroll
    for (int nt = 0; nt < OUT / 16; ++nt) acc[nt] = (f32x4){0.f, 0.f, 0.f, 0.f};
#pragma unroll
    for (int kc = 0; kc < 4; ++kc) {
      uint4 av = *(const uint4*)&Xb[(wv * 16 + l16) * KP + kc * 32 + lg * 8];
      bf16x8 a = as_bf16x8(av);
#pragma unroll
      for (int nt = 0; nt < OUT / 16; ++nt) {
        uint4 bv = *(const uint4*)&Wt[(nt * 16 + l16) * KP + kc * 32 + lg * 8];
        acc[nt] = __builtin_amdgcn_mfma_f32_16x16x32_bf16(a, as_bf16x8(bv), acc[nt], 0, 0, 0);
      }
    }
    int rbase = row0 + wv * 16 + lg * 4;
#pragma unroll
    for (int reg = 0; reg < 4; ++reg) {
      int grow = rbase + reg;
      if (grow < n) {
        float di = dinv[grow];
#pragma unroll
        for (int nt = 0; nt < OUT / 16; ++nt)
          HSb[(long long)grow * OUT + nt * 16 + l16] = bf16_1(acc[nt][reg] * di);
      }
    }
  }
}

// ---------- FUSED: layer-1 aggregate+finalize -> LDS x1 tile -> MFMA @ W2 -> HS2 ----------
// Stage 1 (per 16-row tile): x1[r] = relu(dinv*(HS1[r] + sum HS1[ssrc]) + b1)  -> LDS bf16
// Stage 2: HS2[rows][64] = dinv[row] * (x1_tile @ W2), 4 waves x 4 MFMA (K=128)
__global__ __launch_bounds__(256)
void fused_agg_mm_k(const int* __restrict__ off, const int* __restrict__ ssrc,
                    const uint4* __restrict__ HSv, const float* __restrict__ dinv,
                    const float* __restrict__ b1, const float* __restrict__ W2,
                    unsigned short* __restrict__ H2, int n, int ntiles) {
  constexpr int KP = 136;
  __shared__ unsigned short Wt2[64 * KP];  // W2^T bf16: Wt2[c][k], 17.4 KB
  __shared__ unsigned short X1[16 * KP];   // x1 tile bf16: 16 rows x 128, 4.4 KB

  const int tid = threadIdx.x;
  for (int i = tid; i < 128 * 64; i += 256) {
    int k = i / 64, c = i % 64;
    Wt2[c * KP + k] = bf16_1(W2[i]);
  }
  // stage-1 geometry: 16 lanes/row x 16 rows
  const int lane = tid & 15;
  const int r    = tid >> 4;
  const int c8   = lane * 8;
  const float4 bb0 = *(const float4*)&b1[c8];
  const float4 bb1 = *(const float4*)&b1[c8 + 4];
  // stage-2 geometry
  const int wv = tid >> 6, l = tid & 63, l16 = l & 15, lg = l >> 4;

  for (int t = blockIdx.x; t < ntiles; t += gridDim.x) {
    int row0 = t * 16;
    __syncthreads();  // protect X1 reuse (and first Wt2 write)
    // ---- stage 1: gather + finalize row d, write bf16 to LDS ----
    int d = row0 + r;
    if (d < n) {
      int beg = off[d], end = off[d + 1];
      float acc[8];
      {
        uint4 g = HSv[(long long)d * 16 + lane];  // self-loop term
        acc[0] = bf_lo(g.x); acc[1] = bf_hi(g.x);
        acc[2] = bf_lo(g.y); acc[3] = bf_hi(g.y);
        acc[4] = bf_lo(g.z); acc[5] = bf_hi(g.z);
        acc[6] = bf_lo(g.w); acc[7] = bf_hi(g.w);
      }
      int e = beg;
      for (; e + 4 <= end; e += 4) {
        int s0 = ssrc[e], s1 = ssrc[e + 1], s2 = ssrc[e + 2], s3 = ssrc[e + 3];
        uint4 g0 = HSv[(long long)s0 * 16 + lane];
        uint4 g1 = HSv[(long long)s1 * 16 + lane];
        uint4 g2 = HSv[(long long)s2 * 16 + lane];
        uint4 g3 = HSv[(long long)s3 * 16 + lane];
        acc[0] += (bf_lo(g0.x) + bf_lo(g1.x)) + (bf_lo(g2.x) + bf_lo(g3.x));
        acc[1] += (bf_hi(g0.x) + bf_hi(g1.x)) + (bf_hi(g2.x) + bf_hi(g3.x));
        acc[2] += (bf_lo(g0.y) + bf_lo(g1.y)) + (bf_lo(g2.y) + bf_lo(g3.y));
        acc[3] += (bf_hi(g0.y) + bf_hi(g1.y)) + (bf_hi(g2.y) + bf_hi(g3.y));
        acc[4] += (bf_lo(g0.z) + bf_lo(g1.z)) + (bf_lo(g2.z) + bf_lo(g3.z));
        acc[5] += (bf_hi(g0.z) + bf_hi(g1.z)) + (bf_hi(g2.z) + bf_hi(g3.z));
        acc[6] += (bf_lo(g0.w) + bf_lo(g1.w)) + (bf_lo(g2.w) + bf_lo(g3.w));
        acc[7] += (bf_hi(g0.w) + bf_hi(g1.w)) + (bf_hi(g2.w) + bf_hi(g3.w));
      }
      for (; e < end; ++e) {
        uint4 g = HSv[(long long)ssrc[e] * 16 + lane];
        acc[0] += bf_lo(g.x); acc[1] += bf_hi(g.x);
        acc[2] += bf_lo(g.y); acc[3] += bf_hi(g.y);
        acc[4] += bf_lo(g.z); acc[5] += bf_hi(g.z);
        acc[6] += bf_lo(g.w); acc[7] += bf_hi(g.w);
      }
      float di = dinv[d];
      float y0 = fmaxf(fmaf(di, acc[0], bb0.x), 0.f);
      float y1 = fmaxf(fmaf(di, acc[1], bb0.y), 0.f);
      float y2 = fmaxf(fmaf(di, acc[2], bb0.z), 0.f);
      float y3 = fmaxf(fmaf(di, acc[3], bb0.w), 0.f);
      float y4 = fmaxf(fmaf(di, acc[4], bb1.x), 0.f);
      float y5 = fmaxf(fmaf(di, acc[5], bb1.y), 0.f);
      float y6 = fmaxf(fmaf(di, acc[6], bb1.z), 0.f);
      float y7 = fmaxf(fmaf(di, acc[7], bb1.w), 0.f);
      uint4 p;
      p.x = pk_bf16(y0, y1); p.y = pk_bf16(y2, y3);
      p.z = pk_bf16(y4, y5); p.w = pk_bf16(y6, y7);
      *(uint4*)&X1[r * KP + c8] = p;
    } else {
      *(uint4*)&X1[r * KP + c8] = make_uint4(0, 0, 0, 0);
    }
    __syncthreads();
    // ---- stage 2: wave wv -> output cols [wv*16, wv*16+16) ----
    f32x4 acc2 = (f32x4){0.f, 0.f, 0.f, 0.f};
#pragma unroll
    for (int kc = 0; kc < 4; ++kc) {
      bf16x8 a = as_bf16x8(*(const uint4*)&X1[l16 * KP + kc * 32 + lg * 8]);
      bf16x8 b = as_bf16x8(*(const uint4*)&Wt2[(wv * 16 + l16) * KP + kc * 32 + lg * 8]);
      acc2 = __builtin_amdgcn_mfma_f32_16x16x32_bf16(a, b, acc2, 0, 0, 0);
    }
    int rb = row0 + lg * 4;
#pragma unroll
    for (int reg = 0; reg < 4; ++reg) {
      int grow = rb + reg;
      if (grow < n)
        H2[(long long)grow * 64 + wv * 16 + l16] = bf16_1(acc2[reg] * dinv[grow]);
    }
  }
}

// ---------- CSR aggregate (bf16 gathers, fp32 accumulate) + fused finalize ----------
template<int OUT>
__global__ __launch_bounds__(256)
void aggregate_k(const int* __restrict__ off, const int* __restrict__ ssrc,
                 const uint4* __restrict__ HSv, const float* __restrict__ dinv,
                 const float* __restrict__ bias, float* __restrict__ Y, int n) {
  constexpr int TPR = OUT / 8;
  constexpr int RPB = 256 / TPR;
  const int lane = threadIdx.x % TPR;
  const int r    = threadIdx.x / TPR;
  const int c8   = lane * 8;
  const float4 bb0 = *(const float4*)&bias[c8];
  const float4 bb1 = *(const float4*)&bias[c8 + 4];

  for (int d = blockIdx.x * RPB + r; d < n; d += gridDim.x * RPB) {
    int beg = off[d], end = off[d + 1];
    float acc[8];
    {
      uint4 g = HSv[(long long)d * TPR + lane];
      acc[0] = bf_lo(g.x); acc[1] = bf_hi(g.x);
      acc[2] = bf_lo(g.y); acc[3] = bf_hi(g.y);
      acc[4] = bf_lo(g.z); acc[5] = bf_hi(g.z);
      acc[6] = bf_lo(g.w); acc[7] = bf_hi(g.w);
    }
    int e = beg;
    for (; e + 4 <= end; e += 4) {
      int s0 = ssrc[e], s1 = ssrc[e + 1], s2 = ssrc[e + 2], s3 = ssrc[e + 3];
      uint4 g0 = HSv[(long long)s0 * TPR + lane];
      uint4 g1 = HSv[(long long)s1 * TPR + lane];
      uint4 g2 = HSv[(long long)s2 * TPR + lane];
      uint4 g3 = HSv[(long long)s3 * TPR + lane];
      acc[0] += (bf_lo(g0.x) + bf_lo(g1.x)) + (bf_lo(g2.x) + bf_lo(g3.x));
      acc[1] += (bf_hi(g0.x) + bf_hi(g1.x)) + (bf_hi(g2.x) + bf_hi(g3.x));
      acc[2] += (bf_lo(g0.y) + bf_lo(g1.y)) + (bf_lo(g2.y) + bf_lo(g3.y));
      acc[3] += (bf_hi(g0.y) + bf_hi(g1.y)) + (bf_hi(g2.y) + bf_hi(g3.y));
      acc[4] += (bf_lo(g0.z) + bf_lo(g1.z)) + (bf_lo(g2.z) + bf_lo(g3.z));
      acc[5] += (bf_hi(g0.z) + bf_hi(g1.z)) + (bf_hi(g2.z) + bf_hi(g3.z));
      acc[6] += (bf_lo(g0.w) + bf_lo(g1.w)) + (bf_lo(g2.w) + bf_lo(g3.w));
      acc[7] += (bf_hi(g0.w) + bf_hi(g1.w)) + (bf_hi(g2.w) + bf_hi(g3.w));
    }
    for (; e < end; ++e) {
      uint4 g = HSv[(long long)ssrc[e] * TPR + lane];
      acc[0] += bf_lo(g.x); acc[1] += bf_hi(g.x);
      acc[2] += bf_lo(g.y); acc[3] += bf_hi(g.y);
      acc[4] += bf_lo(g.z); acc[5] += bf_hi(g.z);
      acc[6] += bf_lo(g.w); acc[7] += bf_hi(g.w);
    }
    float di = dinv[d];
    float4 y0, y1;
    y0.x = fmaxf(fmaf(di, acc[0], bb0.x), 0.f);
    y0.y = fmaxf(fmaf(di, acc[1], bb0.y), 0.f);
    y0.z = fmaxf(fmaf(di, acc[2], bb0.z), 0.f);
    y0.w = fmaxf(fmaf(di, acc[3], bb0.w), 0.f);
    y1.x = fmaxf(fmaf(di, acc[4], bb1.x), 0.f);
    y1.y = fmaxf(fmaf(di, acc[5], bb1.y), 0.f);
    y1.z = fmaxf(fmaf(di, acc[6], bb1.z), 0.f);
    y1.w = fmaxf(fmaf(di, acc[7], bb1.w), 0.f);
    *(float4*)&Y[(long long)d * OUT + c8] = y0;
    *(float4*)&Y[(long long)d * OUT + c8 + 4] = y1;
  }
}

extern "C" void kernel_launch(void* const* d_in, const int* in_sizes, int n_in,
                              void* d_out, int out_size, void* d_ws, size_t ws_size,
                              hipStream_t stream) {
  const float* x  = (const float*)d_in[0];
  const int*   ei = (const int*)d_in[1];
  const float* W1 = (const float*)d_in[2];
  const float* b1 = (const float*)d_in[3];
  const float* W2 = (const float*)d_in[4];
  const float* b2 = (const float*)d_in[5];
  float* out = (float*)d_out;

  const int n = in_sizes[0] / IN_DIM;   // 100000
  const int E = in_sizes[1] / 2;        // 1600000

  // workspace layout (bytes)
  char* ws = (char*)d_ws;
  size_t o = 0;
  auto alloc = [&](size_t bytes) { char* p = ws + o; o = (o + bytes + 255) & ~(size_t)255; return p; };
  float* dinv   = (float*)alloc((size_t)n * 4);
  int*   off    = (int*)  alloc((size_t)(n + 1) * 4);
  int*   btot   = (int*)  alloc((size_t)1024 * 4);
  int*   bkbase = (int*)  alloc((size_t)1025 * 4);
  int*   hist   = (int*)  alloc((size_t)G_SORT * 1024 * 4);  // 1 MB
  int*   ssrc   = (int*)  alloc((size_t)E * 4);
  unsigned short* A  = (unsigned short*)alloc((size_t)n * 128 * 2);  // bf16 HS1 (25.6 MB)
  unsigned short* H2 = (unsigned short*)alloc((size_t)n * 64 * 2);   // bf16 HS2 (12.8 MB)
  // ent (6.4 MB) overlays A: only live during CSR build, before HS1 is written
  unsigned* ent = (unsigned*)A;

  const int NB = (n + (1 << BSHIFT) - 1) >> BSHIFT; // 782 buckets (<= 1024 required)
  const int ntiles  = (n + 63) / 64;                // 64-row tiles for mm1
  const int ntiles2 = (n + 15) / 16;                // 16-row tiles for fused agg+mm

  // ----- CSR build (zero global atomics; off/dinv derived in-sort) -----
  hist_k<<<G_SORT, 256, 0, stream>>>(ei, E, NB, hist);
  hsum_k<<<NB, G_SORT, 0, stream>>>(hist, NB, btot);
  bscan_k<<<1, 1024, 0, stream>>>(btot, NB, bkbase, off, n, E);
  fillc_k<<<G_SORT, 256, 0, stream>>>(ei, E, NB, hist, bkbase, ent);
  fill2_k<<<NB, 256, 0, stream>>>(bkbase, ent, ssrc, off, dinv, n);

  // ----- layer 1 matmul (128 -> 128), bf16 HS1 -----
  mfma_matmul_k<128><<<782, 256, 0, stream>>>(x, W1, dinv, A, n, ntiles);

  // ----- fused: layer-1 aggregate+relu+bias, then x1 @ W2 * dinv -> bf16 HS2 -----
  fused_agg_mm_k<<<2048, 256, 0, stream>>>(off, ssrc, (const uint4*)A, dinv, b1, W2,
                                           H2, n, ntiles2);

  // ----- layer 2 aggregate -> final output -----
  aggregate_k<64><<<4096, 256, 0, stream>>>(off, ssrc, (const uint4*)H2, dinv, b2, out, n);
}

// Round 11
// 181.855 us; speedup vs baseline: 4.6951x; 1.0239x over previous
//
#include <hip/hip_runtime.h>

constexpr int IN_DIM = 128;
constexpr int BSHIFT = 7;     // 128 nodes per bucket
constexpr int G_SORT = 256;   // blocks in the counting-sort passes
// NOTE: requires n <= 2^25 (src packs in 25 bits), n <= 1024<<BSHIFT (LDS hist),
// and NB <= 1024 (single-block bucket scan); n=100000 ok.

typedef float  f32x4  __attribute__((ext_vector_type(4)));
typedef short  bf16x8 __attribute__((ext_vector_type(8)));

// bf16 helpers: storage-only compression (accumulate in fp32)
__device__ inline unsigned pk_bf16(float a, float b) {  // RTNE pack of 2 floats
  unsigned ua = __float_as_uint(a), ub = __float_as_uint(b);
  ua += 0x7fff + ((ua >> 16) & 1);
  ub += 0x7fff + ((ub >> 16) & 1);
  return (ua >> 16) | (ub & 0xffff0000u);
}
__device__ inline unsigned short bf16_1(float a) {
  unsigned u = __float_as_uint(a);
  u += 0x7fff + ((u >> 16) & 1);
  return (unsigned short)(u >> 16);
}
__device__ inline float bf_lo(unsigned u) { return __uint_as_float(u << 16); }
__device__ inline float bf_hi(unsigned u) { return __uint_as_float(u & 0xffff0000u); }
__device__ inline bf16x8 as_bf16x8(uint4 v) { bf16x8 r; __builtin_memcpy(&r, &v, 16); return r; }

// ---------- pass A: per-block LDS bucket histograms (no global atomics) ----------
__global__ __launch_bounds__(256)
void hist_k(const int* __restrict__ ei, int E, int K, int* __restrict__ hist) {
  __shared__ int lh[1024];
  for (int i = threadIdx.x; i < K; i += 256) lh[i] = 0;
  __syncthreads();
  int C = (E + gridDim.x - 1) / gridDim.x;
  int beg = blockIdx.x * C;
  int end = min(E, beg + C);
  for (int i = beg + threadIdx.x; i < end; i += 256)
    atomicAdd(&lh[ei[E + i] >> BSHIFT], 1);
  __syncthreads();
  for (int i = threadIdx.x; i < K; i += 256) hist[blockIdx.x * K + i] = lh[i];
}

// ---------- pass B: column-scan hist over blocks; emit bucket totals ----------
__global__ __launch_bounds__(G_SORT)
void hsum_k(int* __restrict__ hist, int K, int* __restrict__ btot) {
  __shared__ int sd[G_SORT];
  int k = blockIdx.x;
  int v = hist[threadIdx.x * K + k];
  sd[threadIdx.x] = v;
  __syncthreads();
#pragma unroll
  for (int ofs = 1; ofs < G_SORT; ofs <<= 1) {
    int t = (threadIdx.x >= ofs) ? sd[threadIdx.x - ofs] : 0;
    __syncthreads();
    sd[threadIdx.x] += t;
    __syncthreads();
  }
  hist[threadIdx.x * K + k] = sd[threadIdx.x] - v;       // exclusive within bucket
  if (threadIdx.x == G_SORT - 1) btot[k] = sd[threadIdx.x];  // bucket total
}

// ---------- pass C: single-block exclusive scan of bucket totals -> bkbase ----------
__global__ __launch_bounds__(1024)
void bscan_k(const int* __restrict__ btot, int NB, int* __restrict__ bkbase,
             int* __restrict__ off, int n, int E) {
  __shared__ int sd[1024];
  int v = (threadIdx.x < NB) ? btot[threadIdx.x] : 0;
  sd[threadIdx.x] = v;
  __syncthreads();
#pragma unroll
  for (int ofs = 1; ofs < 1024; ofs <<= 1) {
    int t = (threadIdx.x >= ofs) ? sd[threadIdx.x - ofs] : 0;
    __syncthreads();
    sd[threadIdx.x] += t;
    __syncthreads();
  }
  if (threadIdx.x < NB) bkbase[threadIdx.x] = sd[threadIdx.x] - v;  // exclusive
  if (threadIdx.x == 0) { bkbase[NB] = E; off[n] = E; }
}

// ---------- pass D: place packed (d_local,src) at reserved positions ----------
__global__ __launch_bounds__(256)
void fillc_k(const int* __restrict__ ei, int E, int K, const int* __restrict__ hist,
             const int* __restrict__ bkbase, unsigned* __restrict__ ent) {
  __shared__ int lcur[1024];
  for (int i = threadIdx.x; i < K; i += 256)
    lcur[i] = bkbase[i] + hist[blockIdx.x * K + i];
  __syncthreads();
  int C = (E + gridDim.x - 1) / gridDim.x;
  int beg = blockIdx.x * C;
  int end = min(E, beg + C);
  for (int i = beg + threadIdx.x; i < end; i += 256) {
    int s = ei[i];
    int d = ei[E + i];
    int pos = atomicAdd(&lcur[d >> BSHIFT], 1);
    ent[pos] = ((unsigned)(d & ((1 << BSHIFT) - 1)) << 25) | (unsigned)s;
  }
}

// ---------- pass E: per-bucket -> node-exact CSR; derive off/dinv as by-products ----------
__global__ __launch_bounds__(256)
void fill2_k(const int* __restrict__ bkbase, const unsigned* __restrict__ ent,
             int* __restrict__ ssrc, int* __restrict__ off, float* __restrict__ dinv,
             int n) {
  constexpr int BK = 1 << BSHIFT;  // 128
  __shared__ int lcnt[BK];
  __shared__ int lbase[BK];
  __shared__ int sd[BK];
  const int tid = threadIdx.x;
  int node0 = blockIdx.x << BSHIFT;
  int nn = min(BK, n - node0);
  int beg = bkbase[blockIdx.x], end = bkbase[blockIdx.x + 1];

  if (tid < BK) lcnt[tid] = 0;
  __syncthreads();
  for (int i = beg + tid; i < end; i += 256)
    atomicAdd(&lcnt[ent[i] >> 25], 1);
  __syncthreads();
  int v = (tid < BK) ? lcnt[tid] : 0;
  if (tid < BK) sd[tid] = v;
  __syncthreads();
#pragma unroll
  for (int ofs = 1; ofs < BK; ofs <<= 1) {
    int t = 0;
    if (tid < BK && tid >= ofs) t = sd[tid - ofs];
    __syncthreads();
    if (tid < BK) sd[tid] += t;
    __syncthreads();
  }
  if (tid < BK) {
    int base = beg + sd[tid] - v;
    lbase[tid] = base;
    lcnt[tid] = 0;
    if (tid < nn) {
      off[node0 + tid] = base;
      dinv[node0 + tid] = rsqrtf((float)v + 1.0f);  // +1 self-loop
    }
  }
  __syncthreads();
  for (int i = beg + tid; i < end; i += 256) {
    unsigned p = ent[i];
    int dl = (int)(p >> 25);
    int s  = (int)(p & ((1u << 25) - 1));
    int pos = lbase[dl] + atomicAdd(&lcnt[dl], 1);
    ssrc[pos] = s;
  }
}

// ---------- MFMA matmul, fp32 input: HSb = dinv * (X @ W), bf16 out ----------
template<int OUT>
__global__ __launch_bounds__(256)
void mfma_matmul_k(const float* __restrict__ X, const float* __restrict__ W,
                   const float* __restrict__ dinv, unsigned short* __restrict__ HSb,
                   int n, int ntiles) {
  constexpr int KP = 136;  // padded K row stride in bf16 (272B)
  __shared__ unsigned short Wt[OUT * KP];
  __shared__ unsigned short Xb[64 * KP];

  const int tid = threadIdx.x;
  for (int i = tid; i < 128 * OUT; i += 256) {
    int k = i / OUT, c = i % OUT;
    Wt[c * KP + k] = bf16_1(W[i]);
  }
  const int wv  = tid >> 6;
  const int l   = tid & 63;
  const int l16 = l & 15, lg = l >> 4;

  for (int t = blockIdx.x; t < ntiles; t += gridDim.x) {
    int row0 = t * 64;
    __syncthreads();
    for (int i = tid; i < 64 * 16; i += 256) {
      int r = i >> 4, kg8 = i & 15;
      int grow = row0 + r;
      uint4 p = make_uint4(0, 0, 0, 0);
      if (grow < n) {
        const float* xp = &X[(long long)grow * 128 + kg8 * 8];
        float4 a = *(const float4*)xp;
        float4 b = *(const float4*)(xp + 4);
        p.x = pk_bf16(a.x, a.y); p.y = pk_bf16(a.z, a.w);
        p.z = pk_bf16(b.x, b.y); p.w = pk_bf16(b.z, b.w);
      }
      *(uint4*)&Xb[r * KP + kg8 * 8] = p;
    }
    __syncthreads();

    f32x4 acc[OUT / 16];
#pragma unroll
    for (int nt = 0; nt < OUT / 16; ++nt) acc[nt] = (f32x4){0.f, 0.f, 0.f, 0.f};
#pragma unroll
    for (int kc = 0; kc < 4; ++kc) {
      uint4 av = *(const uint4*)&Xb[(wv * 16 + l16) * KP + kc * 32 + lg * 8];
      bf16x8 a = as_bf16x8(av);
#pragma unroll
      for (int nt = 0; nt < OUT / 16; ++nt) {
        uint4 bv = *(const uint4*)&Wt[(nt * 16 + l16) * KP + kc * 32 + lg * 8];
        acc[nt] = __builtin_amdgcn_mfma_f32_16x16x32_bf16(a, as_bf16x8(bv), acc[nt], 0, 0, 0);
      }
    }
    int rbase = row0 + wv * 16 + lg * 4;
#pragma unroll
    for (int reg = 0; reg < 4; ++reg) {
      int grow = rbase + reg;
      if (grow < n) {
        float di = dinv[grow];
#pragma unroll
        for (int nt = 0; nt < OUT / 16; ++nt)
          HSb[(long long)grow * OUT + nt * 16 + l16] = bf16_1(acc[nt][reg] * di);
      }
    }
  }
}

// ---------- MFMA matmul, bf16 input (128 -> 64): HSb = dinv * (Xb16 @ W) ----------
__global__ __launch_bounds__(256)
void mfma_matmul_b16_k(const unsigned short* __restrict__ X, const float* __restrict__ W,
                       const float* __restrict__ dinv, unsigned short* __restrict__ HSb,
                       int n, int ntiles) {
  constexpr int OUT = 64;
  constexpr int KP = 136;
  __shared__ unsigned short Wt[OUT * KP];
  __shared__ unsigned short Xb[64 * KP];

  const int tid = threadIdx.x;
  for (int i = tid; i < 128 * OUT; i += 256) {
    int k = i / OUT, c = i % OUT;
    Wt[c * KP + k] = bf16_1(W[i]);
  }
  const int wv  = tid >> 6;
  const int l   = tid & 63;
  const int l16 = l & 15, lg = l >> 4;

  for (int t = blockIdx.x; t < ntiles; t += gridDim.x) {
    int row0 = t * 64;
    __syncthreads();
    // stage bf16 X tile directly (16B per thread per pass, coalesced)
    for (int i = tid; i < 64 * 16; i += 256) {
      int r = i >> 4, kg8 = i & 15;
      int grow = row0 + r;
      uint4 p = make_uint4(0, 0, 0, 0);
      if (grow < n) p = *(const uint4*)&X[(long long)grow * 128 + kg8 * 8];
      *(uint4*)&Xb[r * KP + kg8 * 8] = p;
    }
    __syncthreads();

    f32x4 acc[OUT / 16];
#pragma unroll
    for (int nt = 0; nt < OUT / 16; ++nt) acc[nt] = (f32x4){0.f, 0.f, 0.f, 0.f};
#pragma unroll
    for (int kc = 0; kc < 4; ++kc) {
      uint4 av = *(const uint4*)&Xb[(wv * 16 + l16) * KP + kc * 32 + lg * 8];
      bf16x8 a = as_bf16x8(av);
#pragma unroll
      for (int nt = 0; nt < OUT / 16; ++nt) {
        uint4 bv = *(const uint4*)&Wt[(nt * 16 + l16) * KP + kc * 32 + lg * 8];
        acc[nt] = __builtin_amdgcn_mfma_f32_16x16x32_bf16(a, as_bf16x8(bv), acc[nt], 0, 0, 0);
      }
    }
    int rbase = row0 + wv * 16 + lg * 4;
#pragma unroll
    for (int reg = 0; reg < 4; ++reg) {
      int grow = rbase + reg;
      if (grow < n) {
        float di = dinv[grow];
#pragma unroll
        for (int nt = 0; nt < OUT / 16; ++nt)
          HSb[(long long)grow * OUT + nt * 16 + l16] = bf16_1(acc[nt][reg] * di);
      }
    }
  }
}

// ---------- CSR aggregate (bf16 gathers, fp32 accumulate) + fused finalize ----------
// BOUT=false: Y fp32 (final output). BOUT=true: Y bf16-packed (internal x1).
template<int OUT, bool BOUT>
__global__ __launch_bounds__(256)
void aggregate_k(const int* __restrict__ off, const int* __restrict__ ssrc,
                 const uint4* __restrict__ HSv, const float* __restrict__ dinv,
                 const float* __restrict__ bias, void* __restrict__ Yp, int n) {
  constexpr int TPR = OUT / 8;       // lanes per row: 16 (OUT=128) / 8 (OUT=64)
  constexpr int RPB = 256 / TPR;     // rows per block
  const int lane = threadIdx.x % TPR;
  const int r    = threadIdx.x / TPR;
  const int c8   = lane * 8;
  const float4 bb0 = *(const float4*)&bias[c8];
  const float4 bb1 = *(const float4*)&bias[c8 + 4];

  for (int d = blockIdx.x * RPB + r; d < n; d += gridDim.x * RPB) {
    int beg = off[d], end = off[d + 1];
    float acc[8];
    {
      uint4 g = HSv[(long long)d * TPR + lane];  // self-loop term
      acc[0] = bf_lo(g.x); acc[1] = bf_hi(g.x);
      acc[2] = bf_lo(g.y); acc[3] = bf_hi(g.y);
      acc[4] = bf_lo(g.z); acc[5] = bf_hi(g.z);
      acc[6] = bf_lo(g.w); acc[7] = bf_hi(g.w);
    }
    int e = beg;
    for (; e + 4 <= end; e += 4) {  // 4 independent gathers in flight
      int s0 = ssrc[e], s1 = ssrc[e + 1], s2 = ssrc[e + 2], s3 = ssrc[e + 3];
      uint4 g0 = HSv[(long long)s0 * TPR + lane];
      uint4 g1 = HSv[(long long)s1 * TPR + lane];
      uint4 g2 = HSv[(long long)s2 * TPR + lane];
      uint4 g3 = HSv[(long long)s3 * TPR + lane];
      acc[0] += (bf_lo(g0.x) + bf_lo(g1.x)) + (bf_lo(g2.x) + bf_lo(g3.x));
      acc[1] += (bf_hi(g0.x) + bf_hi(g1.x)) + (bf_hi(g2.x) + bf_hi(g3.x));
      acc[2] += (bf_lo(g0.y) + bf_lo(g1.y)) + (bf_lo(g2.y) + bf_lo(g3.y));
      acc[3] += (bf_hi(g0.y) + bf_hi(g1.y)) + (bf_hi(g2.y) + bf_hi(g3.y));
      acc[4] += (bf_lo(g0.z) + bf_lo(g1.z)) + (bf_lo(g2.z) + bf_lo(g3.z));
      acc[5] += (bf_hi(g0.z) + bf_hi(g1.z)) + (bf_hi(g2.z) + bf_hi(g3.z));
      acc[6] += (bf_lo(g0.w) + bf_lo(g1.w)) + (bf_lo(g2.w) + bf_lo(g3.w));
      acc[7] += (bf_hi(g0.w) + bf_hi(g1.w)) + (bf_hi(g2.w) + bf_hi(g3.w));
    }
    for (; e < end; ++e) {
      uint4 g = HSv[(long long)ssrc[e] * TPR + lane];
      acc[0] += bf_lo(g.x); acc[1] += bf_hi(g.x);
      acc[2] += bf_lo(g.y); acc[3] += bf_hi(g.y);
      acc[4] += bf_lo(g.z); acc[5] += bf_hi(g.z);
      acc[6] += bf_lo(g.w); acc[7] += bf_hi(g.w);
    }
    float di = dinv[d];
    float y0 = fmaxf(fmaf(di, acc[0], bb0.x), 0.f);
    float y1 = fmaxf(fmaf(di, acc[1], bb0.y), 0.f);
    float y2 = fmaxf(fmaf(di, acc[2], bb0.z), 0.f);
    float y3 = fmaxf(fmaf(di, acc[3], bb0.w), 0.f);
    float y4 = fmaxf(fmaf(di, acc[4], bb1.x), 0.f);
    float y5 = fmaxf(fmaf(di, acc[5], bb1.y), 0.f);
    float y6 = fmaxf(fmaf(di, acc[6], bb1.z), 0.f);
    float y7 = fmaxf(fmaf(di, acc[7], bb1.w), 0.f);
    if constexpr (BOUT) {
      uint4 p;
      p.x = pk_bf16(y0, y1); p.y = pk_bf16(y2, y3);
      p.z = pk_bf16(y4, y5); p.w = pk_bf16(y6, y7);
      *(uint4*)&((unsigned short*)Yp)[(long long)d * OUT + c8] = p;
    } else {
      float* Y = (float*)Yp;
      *(float4*)&Y[(long long)d * OUT + c8]     = make_float4(y0, y1, y2, y3);
      *(float4*)&Y[(long long)d * OUT + c8 + 4] = make_float4(y4, y5, y6, y7);
    }
  }
}

extern "C" void kernel_launch(void* const* d_in, const int* in_sizes, int n_in,
                              void* d_out, int out_size, void* d_ws, size_t ws_size,
                              hipStream_t stream) {
  const float* x  = (const float*)d_in[0];
  const int*   ei = (const int*)d_in[1];
  const float* W1 = (const float*)d_in[2];
  const float* b1 = (const float*)d_in[3];
  const float* W2 = (const float*)d_in[4];
  const float* b2 = (const float*)d_in[5];
  float* out = (float*)d_out;

  const int n = in_sizes[0] / IN_DIM;   // 100000
  const int E = in_sizes[1] / 2;        // 1600000

  // workspace layout (bytes)
  char* ws = (char*)d_ws;
  size_t o = 0;
  auto alloc = [&](size_t bytes) { char* p = ws + o; o = (o + bytes + 255) & ~(size_t)255; return p; };
  float* dinv   = (float*)alloc((size_t)n * 4);
  int*   off    = (int*)  alloc((size_t)(n + 1) * 4);
  int*   btot   = (int*)  alloc((size_t)1024 * 4);
  int*   bkbase = (int*)  alloc((size_t)1025 * 4);
  int*   hist   = (int*)  alloc((size_t)G_SORT * 1024 * 4);  // 1 MB
  int*   ssrc   = (int*)  alloc((size_t)E * 4);
  unsigned short* A   = (unsigned short*)alloc((size_t)n * 128 * 2);  // bf16 HS1 (25.6 MB)
  unsigned short* X1b = (unsigned short*)alloc((size_t)n * 128 * 2);  // bf16 x1  (25.6 MB)
  unsigned short* H2  = (unsigned short*)alloc((size_t)n * 64 * 2);   // bf16 HS2 (12.8 MB)
  // ent (6.4 MB) overlays A: only live during CSR build, before HS1 is written
  unsigned* ent = (unsigned*)A;

  const int NB = (n + (1 << BSHIFT) - 1) >> BSHIFT; // 782 buckets (<= 1024 required)
  const int ntiles = (n + 63) / 64;                 // 64-row tiles

  // ----- CSR build (zero global atomics; off/dinv derived in-sort) -----
  hist_k<<<G_SORT, 256, 0, stream>>>(ei, E, NB, hist);
  hsum_k<<<NB, G_SORT, 0, stream>>>(hist, NB, btot);
  bscan_k<<<1, 1024, 0, stream>>>(btot, NB, bkbase, off, n, E);
  fillc_k<<<G_SORT, 256, 0, stream>>>(ei, E, NB, hist, bkbase, ent);
  fill2_k<<<NB, 256, 0, stream>>>(bkbase, ent, ssrc, off, dinv, n);

  // ----- layer 1: matmul (128 -> 128) -> bf16 HS1; aggregate -> bf16 x1 -----
  mfma_matmul_k<128><<<782, 256, 0, stream>>>(x, W1, dinv, A, n, ntiles);
  aggregate_k<128, true><<<4096, 256, 0, stream>>>(off, ssrc, (const uint4*)A, dinv, b1, X1b, n);

  // ----- layer 2: matmul (128 -> 64, bf16 in) -> bf16 HS2; aggregate -> fp32 out -----
  mfma_matmul_b16_k<<<782, 256, 0, stream>>>(X1b, W2, dinv, H2, n, ntiles);
  aggregate_k<64, false><<<4096, 256, 0, stream>>>(off, ssrc, (const uint4*)H2, dinv, b2, out, n);
}

// Round 12
// 180.502 us; speedup vs baseline: 4.7302x; 1.0075x over previous
//
#include <hip/hip_runtime.h>

constexpr int IN_DIM = 128;
constexpr int BSHIFT = 7;     // 128 nodes per bucket
constexpr int G_SORT = 256;   // blocks in the counting-sort passes
// NOTE: requires n <= 2^25 (src packs in 25 bits), n <= 1024<<BSHIFT (LDS hist),
// and NB <= 1024 (single-block bucket scan); n=100000 ok.

typedef float  f32x4  __attribute__((ext_vector_type(4)));
typedef short  bf16x8 __attribute__((ext_vector_type(8)));

// bf16 helpers: storage-only compression (accumulate in fp32)
__device__ inline unsigned pk_bf16(float a, float b) {  // RTNE pack of 2 floats
  unsigned ua = __float_as_uint(a), ub = __float_as_uint(b);
  ua += 0x7fff + ((ua >> 16) & 1);
  ub += 0x7fff + ((ub >> 16) & 1);
  return (ua >> 16) | (ub & 0xffff0000u);
}
__device__ inline unsigned short bf16_1(float a) {
  unsigned u = __float_as_uint(a);
  u += 0x7fff + ((u >> 16) & 1);
  return (unsigned short)(u >> 16);
}
__device__ inline float bf_lo(unsigned u) { return __uint_as_float(u << 16); }
__device__ inline float bf_hi(unsigned u) { return __uint_as_float(u & 0xffff0000u); }
__device__ inline bf16x8 as_bf16x8(uint4 v) { bf16x8 r; __builtin_memcpy(&r, &v, 16); return r; }

// ---------- k1: grid-fused {edge-bucket histogram | x fp32 -> bf16 convert} ----------
__global__ __launch_bounds__(256)
void hist_cvt_k(const int* __restrict__ ei, int E, int K, int* __restrict__ hist,
                const float* __restrict__ x, unsigned short* __restrict__ xs,
                long long nx8) {
  if (blockIdx.x < G_SORT) {
    __shared__ int lh[1024];
    for (int i = threadIdx.x; i < K; i += 256) lh[i] = 0;
    __syncthreads();
    int C = (E + G_SORT - 1) / G_SORT;
    int beg = blockIdx.x * C;
    int end = min(E, beg + C);
    for (int i = beg + threadIdx.x; i < end; i += 256)
      atomicAdd(&lh[ei[E + i] >> BSHIFT], 1);
    __syncthreads();
    for (int i = threadIdx.x; i < K; i += 256) hist[blockIdx.x * K + i] = lh[i];
  } else {
    long long t = (long long)(blockIdx.x - G_SORT) * 256 + threadIdx.x;
    long long stride = (long long)(gridDim.x - G_SORT) * 256;
    for (; t < nx8; t += stride) {
      const float* xp = &x[t * 8];
      float4 a = *(const float4*)xp;
      float4 b = *(const float4*)(xp + 4);
      uint4 p;
      p.x = pk_bf16(a.x, a.y); p.y = pk_bf16(a.z, a.w);
      p.z = pk_bf16(b.x, b.y); p.w = pk_bf16(b.z, b.w);
      *(uint4*)&xs[t * 8] = p;
    }
  }
}

// ---------- k2: column-scan hist over blocks; emit bucket totals ----------
__global__ __launch_bounds__(G_SORT)
void hsum_k(int* __restrict__ hist, int K, int* __restrict__ btot) {
  __shared__ int sd[G_SORT];
  int k = blockIdx.x;
  int v = hist[threadIdx.x * K + k];
  sd[threadIdx.x] = v;
  __syncthreads();
#pragma unroll
  for (int ofs = 1; ofs < G_SORT; ofs <<= 1) {
    int t = (threadIdx.x >= ofs) ? sd[threadIdx.x - ofs] : 0;
    __syncthreads();
    sd[threadIdx.x] += t;
    __syncthreads();
  }
  hist[threadIdx.x * K + k] = sd[threadIdx.x] - v;       // exclusive within bucket
  if (threadIdx.x == G_SORT - 1) btot[k] = sd[threadIdx.x];  // bucket total
}

// ---------- k3: single-block exclusive scan of bucket totals -> bkbase ----------
__global__ __launch_bounds__(1024)
void bscan_k(const int* __restrict__ btot, int NB, int* __restrict__ bkbase,
             int* __restrict__ off, int n, int E) {
  __shared__ int sd[1024];
  int v = (threadIdx.x < NB) ? btot[threadIdx.x] : 0;
  sd[threadIdx.x] = v;
  __syncthreads();
#pragma unroll
  for (int ofs = 1; ofs < 1024; ofs <<= 1) {
    int t = (threadIdx.x >= ofs) ? sd[threadIdx.x - ofs] : 0;
    __syncthreads();
    sd[threadIdx.x] += t;
    __syncthreads();
  }
  if (threadIdx.x < NB) bkbase[threadIdx.x] = sd[threadIdx.x] - v;  // exclusive
  if (threadIdx.x == 0) { bkbase[NB] = E; off[n] = E; }
}

// ---------- k4: place packed (d_local,src) at reserved positions ----------
__global__ __launch_bounds__(256)
void fillc_k(const int* __restrict__ ei, int E, int K, const int* __restrict__ hist,
             const int* __restrict__ bkbase, unsigned* __restrict__ ent) {
  __shared__ int lcur[1024];
  for (int i = threadIdx.x; i < K; i += 256)
    lcur[i] = bkbase[i] + hist[blockIdx.x * K + i];
  __syncthreads();
  int C = (E + gridDim.x - 1) / gridDim.x;
  int beg = blockIdx.x * C;
  int end = min(E, beg + C);
  for (int i = beg + threadIdx.x; i < end; i += 256) {
    int s = ei[i];
    int d = ei[E + i];
    int pos = atomicAdd(&lcur[d >> BSHIFT], 1);
    ent[pos] = ((unsigned)(d & ((1 << BSHIFT) - 1)) << 25) | (unsigned)s;
  }
}

// ---------- k5: per-bucket -> node-exact CSR; derive off/dinv as by-products ----------
__global__ __launch_bounds__(256)
void fill2_k(const int* __restrict__ bkbase, const unsigned* __restrict__ ent,
             int* __restrict__ ssrc, int* __restrict__ off, float* __restrict__ dinv,
             int n) {
  constexpr int BK = 1 << BSHIFT;  // 128
  __shared__ int lcnt[BK];
  __shared__ int lbase[BK];
  __shared__ int sd[BK];
  const int tid = threadIdx.x;
  int node0 = blockIdx.x << BSHIFT;
  int nn = min(BK, n - node0);
  int beg = bkbase[blockIdx.x], end = bkbase[blockIdx.x + 1];

  if (tid < BK) lcnt[tid] = 0;
  __syncthreads();
  for (int i = beg + tid; i < end; i += 256)
    atomicAdd(&lcnt[ent[i] >> 25], 1);
  __syncthreads();
  int v = (tid < BK) ? lcnt[tid] : 0;
  if (tid < BK) sd[tid] = v;
  __syncthreads();
#pragma unroll
  for (int ofs = 1; ofs < BK; ofs <<= 1) {
    int t = 0;
    if (tid < BK && tid >= ofs) t = sd[tid - ofs];
    __syncthreads();
    if (tid < BK) sd[tid] += t;
    __syncthreads();
  }
  if (tid < BK) {
    int base = beg + sd[tid] - v;
    lbase[tid] = base;
    lcnt[tid] = 0;
    if (tid < nn) {
      off[node0 + tid] = base;
      dinv[node0 + tid] = rsqrtf((float)v + 1.0f);  // +1 self-loop
    }
  }
  __syncthreads();
  for (int i = beg + tid; i < end; i += 256) {
    unsigned p = ent[i];
    int dl = (int)(p >> 25);
    int s  = (int)(p & ((1u << 25) - 1));
    int pos = lbase[dl] + atomicAdd(&lcnt[dl], 1);
    ssrc[pos] = s;
  }
}

// ---------- k6: normalized input aggregation ----------
// Z[d] = bf16( dinv_d * ( dinv_d*xs[d] + sum_e dinv_{s_e}*xs[s_e] ) )   [= row of A_hat @ x]
__global__ __launch_bounds__(256)
void aggx_k(const int* __restrict__ off, const int* __restrict__ ssrc,
            const uint4* __restrict__ XSv, const float* __restrict__ dinv,
            unsigned short* __restrict__ Z, int n) {
  constexpr int TPR = 16;   // 16 lanes x 16B = 256B row
  constexpr int RPB = 16;
  const int lane = threadIdx.x & 15;
  const int r    = threadIdx.x >> 4;
  const int c8   = lane * 8;

  for (int d = blockIdx.x * RPB + r; d < n; d += gridDim.x * RPB) {
    int beg = off[d], end = off[d + 1];
    float dd = dinv[d];
    float acc[8];
    {
      uint4 g = XSv[(long long)d * TPR + lane];  // self-loop term * dinv_d
      acc[0] = dd * bf_lo(g.x); acc[1] = dd * bf_hi(g.x);
      acc[2] = dd * bf_lo(g.y); acc[3] = dd * bf_hi(g.y);
      acc[4] = dd * bf_lo(g.z); acc[5] = dd * bf_hi(g.z);
      acc[6] = dd * bf_lo(g.w); acc[7] = dd * bf_hi(g.w);
    }
    int e = beg;
    for (; e + 4 <= end; e += 4) {  // 4 independent gathers in flight
      int s0 = ssrc[e], s1 = ssrc[e + 1], s2 = ssrc[e + 2], s3 = ssrc[e + 3];
      float w0 = dinv[s0], w1 = dinv[s1], w2 = dinv[s2], w3 = dinv[s3];
      uint4 g0 = XSv[(long long)s0 * TPR + lane];
      uint4 g1 = XSv[(long long)s1 * TPR + lane];
      uint4 g2 = XSv[(long long)s2 * TPR + lane];
      uint4 g3 = XSv[(long long)s3 * TPR + lane];
      acc[0] += w0 * bf_lo(g0.x) + w1 * bf_lo(g1.x) + w2 * bf_lo(g2.x) + w3 * bf_lo(g3.x);
      acc[1] += w0 * bf_hi(g0.x) + w1 * bf_hi(g1.x) + w2 * bf_hi(g2.x) + w3 * bf_hi(g3.x);
      acc[2] += w0 * bf_lo(g0.y) + w1 * bf_lo(g1.y) + w2 * bf_lo(g2.y) + w3 * bf_lo(g3.y);
      acc[3] += w0 * bf_hi(g0.y) + w1 * bf_hi(g1.y) + w2 * bf_hi(g2.y) + w3 * bf_hi(g3.y);
      acc[4] += w0 * bf_lo(g0.z) + w1 * bf_lo(g1.z) + w2 * bf_lo(g2.z) + w3 * bf_lo(g3.z);
      acc[5] += w0 * bf_hi(g0.z) + w1 * bf_hi(g1.z) + w2 * bf_hi(g2.z) + w3 * bf_hi(g3.z);
      acc[6] += w0 * bf_lo(g0.w) + w1 * bf_lo(g1.w) + w2 * bf_lo(g2.w) + w3 * bf_lo(g3.w);
      acc[7] += w0 * bf_hi(g0.w) + w1 * bf_hi(g1.w) + w2 * bf_hi(g2.w) + w3 * bf_hi(g3.w);
    }
    for (; e < end; ++e) {
      int s = ssrc[e];
      float w = dinv[s];
      uint4 g = XSv[(long long)s * TPR + lane];
      acc[0] += w * bf_lo(g.x); acc[1] += w * bf_hi(g.x);
      acc[2] += w * bf_lo(g.y); acc[3] += w * bf_hi(g.y);
      acc[4] += w * bf_lo(g.z); acc[5] += w * bf_hi(g.z);
      acc[6] += w * bf_lo(g.w); acc[7] += w * bf_hi(g.w);
    }
    uint4 p;
    p.x = pk_bf16(dd * acc[0], dd * acc[1]);
    p.y = pk_bf16(dd * acc[2], dd * acc[3]);
    p.z = pk_bf16(dd * acc[4], dd * acc[5]);
    p.w = pk_bf16(dd * acc[6], dd * acc[7]);
    *(uint4*)&Z[(long long)d * 128 + c8] = p;
  }
}

// ---------- k7: fused double matmul ----------
// per 64-row tile: x1 = relu(Z @ W1 + b1) (LDS, bf16); H2 = dinv * (x1 @ W2) (bf16 out)
__global__ __launch_bounds__(256)
void mm12_k(const unsigned short* __restrict__ Z, const float* __restrict__ W1,
            const float* __restrict__ b1, const float* __restrict__ W2,
            const float* __restrict__ dinv, unsigned short* __restrict__ H2,
            int n, int ntiles) {
  constexpr int KP = 136;  // padded K row stride in bf16 (272B)
  __shared__ unsigned short W1t[128 * KP];  // 34.8 KB  W1^T: [c][k]
  __shared__ unsigned short W2t[64 * KP];   // 17.4 KB  W2^T: [c][k]
  __shared__ unsigned short T[64 * KP];     // 17.4 KB  Z tile, then x1 tile

  const int tid = threadIdx.x;
  for (int i = tid; i < 128 * 128; i += 256) {
    int k = i >> 7, c = i & 127;
    W1t[c * KP + k] = bf16_1(W1[i]);
  }
  for (int i = tid; i < 128 * 64; i += 256) {
    int k = i / 64, c = i % 64;
    W2t[c * KP + k] = bf16_1(W2[i]);
  }
  const int wv = tid >> 6, l = tid & 63, l16 = l & 15, lg = l >> 4;
  const int rb = wv * 16 + lg * 4;

  for (int t = blockIdx.x; t < ntiles; t += gridDim.x) {
    int row0 = t * 64;
    __syncthreads();  // W staging (first iter) / prev-tile readers done
    for (int i = tid; i < 64 * 16; i += 256) {
      int r = i >> 4, kg8 = i & 15;
      int grow = row0 + r;
      uint4 p = make_uint4(0, 0, 0, 0);
      if (grow < n) p = *(const uint4*)&Z[(long long)grow * 128 + kg8 * 8];
      *(uint4*)&T[r * KP + kg8 * 8] = p;
    }
    __syncthreads();

    // stage 1: rows [wv*16, wv*16+16): acc1 = Ztile @ W1
    f32x4 acc1[8];
#pragma unroll
    for (int nt = 0; nt < 8; ++nt) acc1[nt] = (f32x4){0.f, 0.f, 0.f, 0.f};
#pragma unroll
    for (int kc = 0; kc < 4; ++kc) {
      bf16x8 a = as_bf16x8(*(const uint4*)&T[(wv * 16 + l16) * KP + kc * 32 + lg * 8]);
#pragma unroll
      for (int nt = 0; nt < 8; ++nt) {
        bf16x8 b = as_bf16x8(*(const uint4*)&W1t[(nt * 16 + l16) * KP + kc * 32 + lg * 8]);
        acc1[nt] = __builtin_amdgcn_mfma_f32_16x16x32_bf16(a, b, acc1[nt], 0, 0, 0);
      }
    }
    __syncthreads();  // all waves' Ztile reads done before x1 overwrite
    // epilogue 1: x1 = relu(acc1 + b1) -> T (bf16), rows rb..rb+3, col nt*16+l16
#pragma unroll
    for (int reg = 0; reg < 4; ++reg) {
#pragma unroll
      for (int nt = 0; nt < 8; ++nt) {
        int c = nt * 16 + l16;
        T[(rb + reg) * KP + c] = bf16_1(fmaxf(acc1[nt][reg] + b1[c], 0.f));
      }
    }
    __syncthreads();  // x1 tile complete

    // stage 2: H2 rows [wv*16,+16) = dinv * (x1 @ W2)
    f32x4 acc2[4];
#pragma unroll
    for (int nt = 0; nt < 4; ++nt) acc2[nt] = (f32x4){0.f, 0.f, 0.f, 0.f};
#pragma unroll
    for (int kc = 0; kc < 4; ++kc) {
      bf16x8 a = as_bf16x8(*(const uint4*)&T[(wv * 16 + l16) * KP + kc * 32 + lg * 8]);
#pragma unroll
      for (int nt = 0; nt < 4; ++nt) {
        bf16x8 b = as_bf16x8(*(const uint4*)&W2t[(nt * 16 + l16) * KP + kc * 32 + lg * 8]);
        acc2[nt] = __builtin_amdgcn_mfma_f32_16x16x32_bf16(a, b, acc2[nt], 0, 0, 0);
      }
    }
#pragma unroll
    for (int reg = 0; reg < 4; ++reg) {
      int grow = row0 + rb + reg;
      if (grow < n) {
        float di = dinv[grow];
#pragma unroll
        for (int nt = 0; nt < 4; ++nt)
          H2[(long long)grow * 64 + nt * 16 + l16] = bf16_1(acc2[nt][reg] * di);
      }
    }
  }
}

// ---------- k8: layer-2 aggregate (bf16 gathers, fp32 accumulate) -> fp32 out ----------
__global__ __launch_bounds__(256)
void agg2_k(const int* __restrict__ off, const int* __restrict__ ssrc,
            const uint4* __restrict__ HSv, const float* __restrict__ dinv,
            const float* __restrict__ bias, float* __restrict__ Y, int n) {
  constexpr int TPR = 8;    // 8 lanes x 16B = 128B row
  constexpr int RPB = 32;
  const int lane = threadIdx.x % TPR;
  const int r    = threadIdx.x / TPR;
  const int c8   = lane * 8;
  const float4 bb0 = *(const float4*)&bias[c8];
  const float4 bb1 = *(const float4*)&bias[c8 + 4];

  for (int d = blockIdx.x * RPB + r; d < n; d += gridDim.x * RPB) {
    int beg = off[d], end = off[d + 1];
    float acc[8];
    {
      uint4 g = HSv[(long long)d * TPR + lane];  // self-loop term
      acc[0] = bf_lo(g.x); acc[1] = bf_hi(g.x);
      acc[2] = bf_lo(g.y); acc[3] = bf_hi(g.y);
      acc[4] = bf_lo(g.z); acc[5] = bf_hi(g.z);
      acc[6] = bf_lo(g.w); acc[7] = bf_hi(g.w);
    }
    int e = beg;
    for (; e + 4 <= end; e += 4) {
      int s0 = ssrc[e], s1 = ssrc[e + 1], s2 = ssrc[e + 2], s3 = ssrc[e + 3];
      uint4 g0 = HSv[(long long)s0 * TPR + lane];
      uint4 g1 = HSv[(long long)s1 * TPR + lane];
      uint4 g2 = HSv[(long long)s2 * TPR + lane];
      uint4 g3 = HSv[(long long)s3 * TPR + lane];
      acc[0] += (bf_lo(g0.x) + bf_lo(g1.x)) + (bf_lo(g2.x) + bf_lo(g3.x));
      acc[1] += (bf_hi(g0.x) + bf_hi(g1.x)) + (bf_hi(g2.x) + bf_hi(g3.x));
      acc[2] += (bf_lo(g0.y) + bf_lo(g1.y)) + (bf_lo(g2.y) + bf_lo(g3.y));
      acc[3] += (bf_hi(g0.y) + bf_hi(g1.y)) + (bf_hi(g2.y) + bf_hi(g3.y));
      acc[4] += (bf_lo(g0.z) + bf_lo(g1.z)) + (bf_lo(g2.z) + bf_lo(g3.z));
      acc[5] += (bf_hi(g0.z) + bf_hi(g1.z)) + (bf_hi(g2.z) + bf_hi(g3.z));
      acc[6] += (bf_lo(g0.w) + bf_lo(g1.w)) + (bf_lo(g2.w) + bf_lo(g3.w));
      acc[7] += (bf_hi(g0.w) + bf_hi(g1.w)) + (bf_hi(g2.w) + bf_hi(g3.w));
    }
    for (; e < end; ++e) {
      uint4 g = HSv[(long long)ssrc[e] * TPR + lane];
      acc[0] += bf_lo(g.x); acc[1] += bf_hi(g.x);
      acc[2] += bf_lo(g.y); acc[3] += bf_hi(g.y);
      acc[4] += bf_lo(g.z); acc[5] += bf_hi(g.z);
      acc[6] += bf_lo(g.w); acc[7] += bf_hi(g.w);
    }
    float di = dinv[d];
    float4 y0, y1;
    y0.x = fmaxf(fmaf(di, acc[0], bb0.x), 0.f);
    y0.y = fmaxf(fmaf(di, acc[1], bb0.y), 0.f);
    y0.z = fmaxf(fmaf(di, acc[2], bb0.z), 0.f);
    y0.w = fmaxf(fmaf(di, acc[3], bb0.w), 0.f);
    y1.x = fmaxf(fmaf(di, acc[4], bb1.x), 0.f);
    y1.y = fmaxf(fmaf(di, acc[5], bb1.y), 0.f);
    y1.z = fmaxf(fmaf(di, acc[6], bb1.z), 0.f);
    y1.w = fmaxf(fmaf(di, acc[7], bb1.w), 0.f);
    *(float4*)&Y[(long long)d * 64 + c8]     = y0;
    *(float4*)&Y[(long long)d * 64 + c8 + 4] = y1;
  }
}

extern "C" void kernel_launch(void* const* d_in, const int* in_sizes, int n_in,
                              void* d_out, int out_size, void* d_ws, size_t ws_size,
                              hipStream_t stream) {
  const float* x  = (const float*)d_in[0];
  const int*   ei = (const int*)d_in[1];
  const float* W1 = (const float*)d_in[2];
  const float* b1 = (const float*)d_in[3];
  const float* W2 = (const float*)d_in[4];
  const float* b2 = (const float*)d_in[5];
  float* out = (float*)d_out;

  const int n = in_sizes[0] / IN_DIM;   // 100000
  const int E = in_sizes[1] / 2;        // 1600000

  // workspace layout (bytes)
  char* ws = (char*)d_ws;
  size_t o = 0;
  auto alloc = [&](size_t bytes) { char* p = ws + o; o = (o + bytes + 255) & ~(size_t)255; return p; };
  float* dinv   = (float*)alloc((size_t)n * 4);
  int*   off    = (int*)  alloc((size_t)(n + 1) * 4);
  int*   btot   = (int*)  alloc((size_t)1024 * 4);
  int*   bkbase = (int*)  alloc((size_t)1025 * 4);
  int*   hist   = (int*)  alloc((size_t)G_SORT * 1024 * 4);  // 1 MB
  int*   ssrc   = (int*)  alloc((size_t)E * 4);
  unsigned short* xs = (unsigned short*)alloc((size_t)n * 128 * 2);  // bf16 x (25.6 MB)
  unsigned short* Z  = (unsigned short*)alloc((size_t)n * 128 * 2);  // bf16 A_hat@x (25.6 MB)
  unsigned short* H2 = (unsigned short*)alloc((size_t)n * 64 * 2);   // bf16 HS2 (12.8 MB)
  // ent (6.4 MB) overlays Z: live only fillc->fill2, before Z is written (aggx)
  unsigned* ent = (unsigned*)Z;

  const int NB = (n + (1 << BSHIFT) - 1) >> BSHIFT; // 782 buckets (<= 1024 required)
  const int ntiles = (n + 63) / 64;                 // 64-row tiles
  const long long nx8 = (long long)n * (IN_DIM / 8);

  // k1: hist (blocks 0..255) || x->bf16 convert (blocks 256..1279)
  hist_cvt_k<<<G_SORT + 1024, 256, 0, stream>>>(ei, E, NB, hist, x, xs, nx8);
  // k2..k5: counting-sort CSR build; off/dinv derived in-sort
  hsum_k<<<NB, G_SORT, 0, stream>>>(hist, NB, btot);
  bscan_k<<<1, 1024, 0, stream>>>(btot, NB, bkbase, off, n, E);
  fillc_k<<<G_SORT, 256, 0, stream>>>(ei, E, NB, hist, bkbase, ent);
  fill2_k<<<NB, 256, 0, stream>>>(bkbase, ent, ssrc, off, dinv, n);

  // k6: Z = A_hat @ x  (normalized aggregation of bf16 x)
  aggx_k<<<4096, 256, 0, stream>>>(off, ssrc, (const uint4*)xs, dinv, Z, n);

  // k7: H2 = dinv * (relu(Z@W1 + b1) @ W2)   (fused double matmul)
  mm12_k<<<782, 256, 0, stream>>>(Z, W1, b1, W2, dinv, H2, n, ntiles);

  // k8: out = relu(dinv*(H2_d + sum H2_s) + b2)
  agg2_k<<<4096, 256, 0, stream>>>(off, ssrc, (const uint4*)H2, dinv, b2, out, n);
}